// Round 1
// baseline (3958.579 us; speedup 1.0000x reference)
//
#include <hip/hip_runtime.h>
#include <hip/hip_bf16.h>
#include <cstdint>
#include <cstddef>

#define B_    16
#define SEQ_  512
#define CIN_  321
#define PRED_ 96
#define DM_   512
#define DI_   1024
#define NST_  16
#define RNK_  32
#define L_    321
#define NT_   (B_*CIN_)   // 5136 tokens

__device__ __forceinline__ float sigmoidf_(float x){ return 1.f/(1.f+__expf(-x)); }
__device__ __forceinline__ float softplusf_(float x){ return (x>20.f) ? x : log1pf(__expf(x)); }

// ============================ GEMM (TN, fp32) ============================
// C[m,n] = sum_k A[m*lda+k] * Bw[n*ldb+k]; epilogue does the store.
// K must be a multiple of 32. M,N guarded.
struct EpiStore {
    float* C; int ldc;
    __device__ void operator()(int m, int n, float v) const { C[(size_t)m*ldc + n] = v; }
};
struct EpiBias {
    float* C; int ldc; const float* bias;
    __device__ void operator()(int m, int n, float v) const { C[(size_t)m*ldc + n] = v + bias[n]; }
};
struct EpiSoftplusBias {
    float* C; int ldc; const float* bias;
    __device__ void operator()(int m, int n, float v) const {
        C[(size_t)m*ldc + n] = softplusf_(v + bias[n]);
    }
};
struct EpiAccFlip {
    float* C; int ldc; int flip;
    __device__ void operator()(int m, int n, float v) const {
        int mm = m;
        if (flip) { int b = m / L_; int l = m - b*L_; mm = b*L_ + (L_-1 - l); }
        C[(size_t)mm*ldc + n] += v;
    }
};
struct EpiHead {
    float* out; const float* bias; const float* mean; const float* stdv;
    const float* rw; const float* rb;
    __device__ void operator()(int m, int n, float v) const {
        int b = m / CIN_, c = m - b*CIN_;
        float o = v + bias[n];
        o = (o - rb[c]) / (rw[c] + 1e-10f);
        o = o * stdv[m] + mean[m];
        out[((size_t)b*PRED_ + n)*CIN_ + c] = o;
    }
};

template<typename Epi>
__global__ __launch_bounds__(256) void gemm_tn(const float* __restrict__ A, int lda,
                                               const float* __restrict__ Bw, int ldb,
                                               int M, int N, int K, Epi epi)
{
    constexpr int BM = 64, BN = 64, BK = 32;
    __shared__ __align__(16) float As[BK][BM+4];
    __shared__ __align__(16) float Bs[BK][BN+4];
    const int tid = threadIdx.x;
    const int m0 = blockIdx.x * BM;
    const int n0 = blockIdx.y * BN;
    const int tx = tid & 15, ty = tid >> 4;
    const int ka = tid & (BK-1);    // 0..31
    const int ra = tid >> 5;        // 0..7

    float acc[4][4] = {};
    for (int k0 = 0; k0 < K; k0 += BK) {
        #pragma unroll
        for (int i = 0; i < 8; ++i) {
            int m = ra + i*8;
            int gm = m0 + m;
            float v = 0.f;
            if (gm < M) v = A[(size_t)gm*lda + k0 + ka];
            As[ka][m] = v;
        }
        #pragma unroll
        for (int i = 0; i < 8; ++i) {
            int n = ra + i*8;
            int gn = n0 + n;
            float v = 0.f;
            if (gn < N) v = Bw[(size_t)gn*ldb + k0 + ka];
            Bs[ka][n] = v;
        }
        __syncthreads();
        #pragma unroll
        for (int kk = 0; kk < BK; ++kk) {
            float a4[4], b4[4];
            #pragma unroll
            for (int i = 0; i < 4; ++i) a4[i] = As[kk][ty*4 + i];
            #pragma unroll
            for (int j = 0; j < 4; ++j) b4[j] = Bs[kk][tx*4 + j];
            #pragma unroll
            for (int i = 0; i < 4; ++i)
                #pragma unroll
                for (int j = 0; j < 4; ++j)
                    acc[i][j] += a4[i] * b4[j];
        }
        __syncthreads();
    }
    #pragma unroll
    for (int i = 0; i < 4; ++i) {
        int m = m0 + ty*4 + i;
        if (m >= M) continue;
        #pragma unroll
        for (int j = 0; j < 4; ++j) {
            int n = n0 + tx*4 + j;
            if (n >= N) continue;
            epi(m, n, acc[i][j]);
        }
    }
}

// ============================ RevIN stats ============================
// grid (B, 6), block 256. mean/std per (b,c) over SEQ.
__global__ __launch_bounds__(256) void revin_stats(const float* __restrict__ x,
                                                   float* __restrict__ meanb,
                                                   float* __restrict__ stdb)
{
    int b = blockIdx.x;
    int c0 = blockIdx.y * 64;
    int cl = threadIdx.x & 63;
    int sl = threadIdx.x >> 6;  // 0..3
    int c = c0 + cl;
    float sum = 0.f, sq = 0.f;
    if (c < CIN_) {
        for (int s = sl; s < SEQ_; s += 4) {
            float v = x[((size_t)b*SEQ_ + s)*CIN_ + c];
            sum += v; sq += v*v;
        }
    }
    __shared__ float ssum[4][64], ssq[4][64];
    ssum[sl][cl] = sum; ssq[sl][cl] = sq;
    __syncthreads();
    if (sl == 0 && c < CIN_) {
        float s = ssum[0][cl]+ssum[1][cl]+ssum[2][cl]+ssum[3][cl];
        float q = ssq[0][cl]+ssq[1][cl]+ssq[2][cl]+ssq[3][cl];
        float mn = s * (1.f/SEQ_);
        float var = q * (1.f/SEQ_) - mn*mn;
        meanb[b*CIN_ + c] = mn;
        stdb[b*CIN_ + c]  = sqrtf(var + 1e-5f);
    }
}

// ============================ normalize + transpose ============================
// x (B,SEQ,CIN) -> xt (B,CIN,SEQ) normalized. grid (B, 8, 6), block 256.
__global__ __launch_bounds__(256) void norm_transpose(const float* __restrict__ x,
                                                      const float* __restrict__ meanb,
                                                      const float* __restrict__ stdb,
                                                      const float* __restrict__ rw,
                                                      const float* __restrict__ rb,
                                                      float* __restrict__ xt)
{
    __shared__ float tile[64][65];
    int b = blockIdx.x, s0 = blockIdx.y*64, c0 = blockIdx.z*64;
    int cl = threadIdx.x & 63, sl = threadIdx.x >> 6;
    #pragma unroll
    for (int i = 0; i < 16; ++i) {
        int s = s0 + sl + i*4;
        int c = c0 + cl;
        float v = 0.f;
        if (c < CIN_) v = x[((size_t)b*SEQ_ + s)*CIN_ + c];
        tile[sl + i*4][cl] = v;
    }
    __syncthreads();
    int sl2 = threadIdx.x & 63, cl2 = threadIdx.x >> 6;
    #pragma unroll
    for (int i = 0; i < 16; ++i) {
        int c = c0 + cl2 + i*4;
        if (c >= CIN_) continue;
        int m = b*CIN_ + c;
        float v = tile[sl2][cl2 + i*4];
        v = (v - meanb[m]) / stdb[m] * rw[c] + rb[c];
        xt[(size_t)m*SEQ_ + s0 + sl2] = v;
    }
}

// ============================ flip tokens ============================
// dst[(b,l)] = src[(b, L-1-l)] for DM_ features. grid NT_*DM_/256.
__global__ __launch_bounds__(256) void flip_tokens(const float* __restrict__ src,
                                                   float* __restrict__ dst)
{
    size_t i = (size_t)blockIdx.x*256 + threadIdx.x;
    int m = (int)(i / DM_), j = (int)(i % DM_);
    int b = m / L_, l = m - b*L_;
    dst[i] = src[((size_t)(b*L_ + (L_-1 - l)))*DM_ + j];
}

// ============================ depthwise causal conv + SiLU ============================
// xc[b,l,d] = silu(cb[d] + sum_j xr[b,l-3+j,d]*cw[d,j]); xr = xz[:, :DI_]
__global__ __launch_bounds__(256) void conv_silu(const float* __restrict__ xz,
                                                 const float* __restrict__ cw,
                                                 const float* __restrict__ cb,
                                                 float* __restrict__ xc, int im)
{
    int m = blockIdx.x;  // b*L_+l
    int d = blockIdx.y*256 + threadIdx.x;
    int b = m / L_, l = m - b*L_;
    float4 w = ((const float4*)cw)[(size_t)im*DI_ + d];
    float wv[4] = {w.x, w.y, w.z, w.w};
    float a = cb[im*DI_ + d];
    #pragma unroll
    for (int j = 0; j < 4; ++j) {
        int ls = l - 3 + j;
        if (ls >= 0) a += xz[((size_t)(b*L_ + ls))*(2*DI_) + d] * wv[j];
    }
    xc[(size_t)m*DI_ + d] = a * sigmoidf_(a);
}

// ============================ selective scan ============================
// One thread per (b,d). In-place: reads delta from `dl`, writes gated y to `dl`.
// grid 64 blocks (16 b x 4 chunks), block 256.
__global__ __launch_bounds__(256) void scan_kernel(float* __restrict__ dl,
                                                   const float* __restrict__ xc,
                                                   const float* __restrict__ xz,
                                                   const float* __restrict__ dbl,
                                                   const float* __restrict__ A_log,
                                                   const float* __restrict__ Dp,
                                                   int im)
{
    int b = blockIdx.x >> 2;
    int d = (blockIdx.x & 3)*256 + threadIdx.x;
    float a[NST_];
    #pragma unroll
    for (int n = 0; n < NST_; ++n)
        a[n] = -__expf(A_log[((size_t)im*DI_ + d)*NST_ + n]);
    float Dd = Dp[im*DI_ + d];
    float h[NST_] = {};
    __shared__ float sB[2][NST_], sC[2][NST_];
    for (int t = 0; t < L_; ++t) {
        int buf = t & 1;
        if (threadIdx.x < 32) {
            float v = dbl[((size_t)(b*L_ + t))*64 + 32 + threadIdx.x];
            if (threadIdx.x < 16) sB[buf][threadIdx.x] = v;
            else                  sC[buf][threadIdx.x - 16] = v;
        }
        __syncthreads();
        size_t base = (size_t)(b*L_ + t);
        float dv = dl[base*DI_ + d];
        float xv = xc[base*DI_ + d];
        float zv = xz[base*(2*DI_) + DI_ + d];
        float du = dv * xv;
        float y = 0.f;
        #pragma unroll
        for (int n = 0; n < NST_; ++n) {
            float dA = __expf(dv * a[n]);
            h[n] = dA*h[n] + du*sB[buf][n];
            y += h[n]*sC[buf][n];
        }
        y = (y + Dd*xv) * (zv * sigmoidf_(zv));
        dl[base*DI_ + d] = y;
    }
}

// ============================ launch ============================
extern "C" void kernel_launch(void* const* d_in, const int* in_sizes, int n_in,
                              void* d_out, int out_size, void* d_ws, size_t ws_size,
                              hipStream_t stream)
{
    const float* x      = (const float*)d_in[0];
    const float* rw     = (const float*)d_in[1];
    const float* rb     = (const float*)d_in[2];
    const float* lin1_w = (const float*)d_in[3];
    const float* lin1_b = (const float*)d_in[4];
    const float* head_w = (const float*)d_in[5];
    const float* head_b = (const float*)d_in[6];
    const float* ipw    = (const float*)d_in[7];
    const float* cw     = (const float*)d_in[8];
    const float* cb     = (const float*)d_in[9];
    const float* xpw    = (const float*)d_in[10];
    const float* dpw    = (const float*)d_in[11];
    const float* dpb    = (const float*)d_in[12];
    const float* A_log  = (const float*)d_in[13];
    const float* Dp     = (const float*)d_in[14];
    const float* opw    = (const float*)d_in[15];
    float* out = (float*)d_out;

    float* ws = (float*)d_ws;
    size_t off = 0;
    auto alloc = [&](size_t n) { float* p = ws + off; off += (n + 63) & ~(size_t)63; return p; };
    float* meanb = alloc(NT_);
    float* stdb  = alloc(NT_);
    float* xnt   = alloc((size_t)NT_*SEQ_);      // also reused as flipped-t buffer
    float* tb0   = alloc((size_t)NT_*DM_);
    float* tb1   = alloc((size_t)NT_*DM_);
    float* xz    = alloc((size_t)NT_*2*DI_);
    float* xc    = alloc((size_t)NT_*DI_);
    float* dl    = alloc((size_t)NT_*DI_);       // delta, then gated y (in place)
    float* dblb  = alloc((size_t)NT_*64);
    (void)ws_size; (void)in_sizes; (void)n_in; (void)out_size;

    dim3 blk(256);
    const int MT = (NT_ + 63) / 64;   // 81 m-tiles

    revin_stats<<<dim3(B_, 6), blk, 0, stream>>>(x, meanb, stdb);
    norm_transpose<<<dim3(B_, 8, 6), blk, 0, stream>>>(x, meanb, stdb, rw, rb, xnt);
    gemm_tn<<<dim3(MT, DM_/64), blk, 0, stream>>>(xnt, SEQ_, lin1_w, SEQ_, NT_, DM_, SEQ_,
                                                  EpiBias{tb0, DM_, lin1_b});

    float* tin = tb0; float* tout = tb1;
    for (int layer = 0; layer < 2; ++layer) {
        hipMemcpyAsync(tout, tin, (size_t)NT_*DM_*sizeof(float), hipMemcpyDeviceToDevice, stream);
        for (int dir = 0; dir < 2; ++dir) {
            const int im = dir;
            const float* Ain = tin;
            if (dir == 1) {
                flip_tokens<<<dim3((NT_*DM_)/256), blk, 0, stream>>>(tin, xnt);
                Ain = xnt;
            }
            // in_proj: (NT, 2*DI) = Ain(NT,DM) @ ipw[im]^T
            gemm_tn<<<dim3(MT, (2*DI_)/64), blk, 0, stream>>>(Ain, DM_, ipw + (size_t)im*2*DI_*DM_, DM_,
                                                              NT_, 2*DI_, DM_, EpiStore{xz, 2*DI_});
            conv_silu<<<dim3(NT_, DI_/256), blk, 0, stream>>>(xz, cw, cb, xc, im);
            // x_proj: (NT, 64) = xc @ xpw[im]^T
            gemm_tn<<<dim3(MT, 1), blk, 0, stream>>>(xc, DI_, xpw + (size_t)im*64*DI_, DI_,
                                                     NT_, 64, DI_, EpiStore{dblb, 64});
            // delta: softplus(dt @ dpw[im]^T + dpb[im]) ; dt = dblb[:, :32]
            gemm_tn<<<dim3(MT, DI_/64), blk, 0, stream>>>(dblb, 64, dpw + (size_t)im*DI_*RNK_, RNK_,
                                                          NT_, DI_, RNK_,
                                                          EpiSoftplusBias{dl, DI_, dpb + im*DI_});
            scan_kernel<<<dim3(64), blk, 0, stream>>>(dl, xc, xz, dblb, A_log, Dp, im);
            // out_proj accumulate into tout (flipped rows for dir=1)
            gemm_tn<<<dim3(MT, DM_/64), blk, 0, stream>>>(dl, DI_, opw + (size_t)im*DM_*DI_, DI_,
                                                          NT_, DM_, DI_, EpiAccFlip{tout, DM_, dir});
        }
        float* tmp = tin; tin = tout; tout = tmp;
    }
    gemm_tn<<<dim3(MT, (PRED_+63)/64), blk, 0, stream>>>(tin, DM_, head_w, DM_, NT_, PRED_, DM_,
                                                         EpiHead{out, head_b, meanb, stdb, rw, rb});
}

// Round 2
// 2634.738 us; speedup vs baseline: 1.5025x; 1.5025x over previous
//
#include <hip/hip_runtime.h>
#include <hip/hip_bf16.h>
#include <cstdint>
#include <cstddef>

#define B_    16
#define SEQ_  512
#define CIN_  321
#define PRED_ 96
#define DM_   512
#define DI_   1024
#define NST_  16
#define RNK_  32
#define L_    321
#define NT_   (B_*CIN_)   // 5136 tokens

__device__ __forceinline__ float sigmoidf_(float x){ return 1.f/(1.f+__expf(-x)); }
__device__ __forceinline__ float softplusf_(float x){ return (x>20.f) ? x : log1pf(__expf(x)); }
__device__ __forceinline__ unsigned short f2bf(float f){
    union { float f; unsigned u; } v; v.f = f;
    unsigned r = v.u + 0x7FFF + ((v.u >> 16) & 1);
    return (unsigned short)(r >> 16);
}

typedef __bf16 bf16x8 __attribute__((ext_vector_type(8)));
typedef float  f32x4  __attribute__((ext_vector_type(4)));

// ============================ epilogues ============================
struct EpiStore {
    float* C; int ldc;
    __device__ void operator()(int m, int n, float v) const { C[(size_t)m*ldc + n] = v; }
};
struct EpiBias {
    float* C; int ldc; const float* bias;
    __device__ void operator()(int m, int n, float v) const { C[(size_t)m*ldc + n] = v + bias[n]; }
};
struct EpiSoftplusBias {
    float* C; int ldc; const float* bias;
    __device__ void operator()(int m, int n, float v) const {
        C[(size_t)m*ldc + n] = softplusf_(v + bias[n]);
    }
};
struct EpiAccFlip {
    float* C; int ldc; int flip;
    __device__ void operator()(int m, int n, float v) const {
        int mm = m;
        if (flip) { int b = m / L_; int l = m - b*L_; mm = b*L_ + (L_-1 - l); }
        C[(size_t)mm*ldc + n] += v;
    }
};
struct EpiHead {
    float* out; const float* bias; const float* mean; const float* stdv;
    const float* rw; const float* rb;
    __device__ void operator()(int m, int n, float v) const {
        int b = m / CIN_, c = m - b*CIN_;
        float o = v + bias[n];
        o = (o - rb[c]) / (rw[c] + 1e-10f);
        o = o * stdv[m] + mean[m];
        out[((size_t)b*PRED_ + n)*CIN_ + c] = o;
    }
};

// ============================ bf16 MFMA GEMM (TN) ============================
// C[m,n] = sum_k A[m*lda+k] * Bw[n*ldb+k]. K % 32 == 0, lda/ldb % 4 == 0.
// fp32 inputs converted to bf16 during LDS staging; fp32 accumulate.
#define PADK 40   // 32 + 8 pad: b128 frag reads land 2-way max (free)

template<typename Epi>
__global__ __launch_bounds__(256) void gemm_mfma(const float* __restrict__ A, int lda,
                                                 const float* __restrict__ Bw, int ldb,
                                                 int M, int N, int K, Epi epi)
{
    __shared__ __align__(16) unsigned short As[128*PADK];
    __shared__ __align__(16) unsigned short Bs[128*PADK];
    const int tid  = threadIdx.x;
    const int m0 = blockIdx.x * 128, n0 = blockIdx.y * 128;
    const int wave = tid >> 6, lane = tid & 63;
    const int wm = (wave & 1) * 64, wn = (wave >> 1) * 64;
    const int ln16 = lane & 15, quad = lane >> 4;
    const int kq = (tid & 7) * 4;   // staging: k offset (float4)
    const int r0 = tid >> 3;        // staging: row 0..31

    f32x4 acc[4][4] = {};
    for (int k0 = 0; k0 < K; k0 += 32) {
        #pragma unroll
        for (int i = 0; i < 4; ++i) {
            int r = r0 + i*32;
            int gm = m0 + r;
            float4 v = make_float4(0.f,0.f,0.f,0.f);
            if (gm < M) v = *(const float4*)(A + (size_t)gm*lda + k0 + kq);
            ushort4 u; u.x=f2bf(v.x); u.y=f2bf(v.y); u.z=f2bf(v.z); u.w=f2bf(v.w);
            *(ushort4*)(As + r*PADK + kq) = u;
        }
        #pragma unroll
        for (int i = 0; i < 4; ++i) {
            int r = r0 + i*32;
            int gn = n0 + r;
            float4 v = make_float4(0.f,0.f,0.f,0.f);
            if (gn < N) v = *(const float4*)(Bw + (size_t)gn*ldb + k0 + kq);
            ushort4 u; u.x=f2bf(v.x); u.y=f2bf(v.y); u.z=f2bf(v.z); u.w=f2bf(v.w);
            *(ushort4*)(Bs + r*PADK + kq) = u;
        }
        __syncthreads();
        bf16x8 af[4], bfr[4];
        #pragma unroll
        for (int i = 0; i < 4; ++i)
            af[i] = *(const bf16x8*)(As + (wm + i*16 + ln16)*PADK + quad*8);
        #pragma unroll
        for (int i = 0; i < 4; ++i)
            bfr[i] = *(const bf16x8*)(Bs + (wn + i*16 + ln16)*PADK + quad*8);
        #pragma unroll
        for (int mi = 0; mi < 4; ++mi)
            #pragma unroll
            for (int ni = 0; ni < 4; ++ni)
                acc[mi][ni] = __builtin_amdgcn_mfma_f32_16x16x32_bf16(af[mi], bfr[ni], acc[mi][ni], 0, 0, 0);
        __syncthreads();
    }
    #pragma unroll
    for (int mi = 0; mi < 4; ++mi) {
        #pragma unroll
        for (int r = 0; r < 4; ++r) {
            int m = m0 + wm + mi*16 + quad*4 + r;
            if (m >= M) continue;
            #pragma unroll
            for (int ni = 0; ni < 4; ++ni) {
                int n = n0 + wn + ni*16 + ln16;
                if (n < N) epi(m, n, acc[mi][ni][r]);
            }
        }
    }
}

// ============================ fp32 GEMM (TN) — small matmuls ============================
template<typename Epi>
__global__ __launch_bounds__(256) void gemm_tn(const float* __restrict__ A, int lda,
                                               const float* __restrict__ Bw, int ldb,
                                               int M, int N, int K, Epi epi)
{
    constexpr int BM = 64, BN = 64, BK = 32;
    __shared__ __align__(16) float As[BK][BM+4];
    __shared__ __align__(16) float Bs[BK][BN+4];
    const int tid = threadIdx.x;
    const int m0 = blockIdx.x * BM;
    const int n0 = blockIdx.y * BN;
    const int tx = tid & 15, ty = tid >> 4;
    const int ka = tid & (BK-1);
    const int ra = tid >> 5;

    float acc[4][4] = {};
    for (int k0 = 0; k0 < K; k0 += BK) {
        #pragma unroll
        for (int i = 0; i < 8; ++i) {
            int m = ra + i*8;
            int gm = m0 + m;
            float v = 0.f;
            if (gm < M) v = A[(size_t)gm*lda + k0 + ka];
            As[ka][m] = v;
        }
        #pragma unroll
        for (int i = 0; i < 8; ++i) {
            int n = ra + i*8;
            int gn = n0 + n;
            float v = 0.f;
            if (gn < N) v = Bw[(size_t)gn*ldb + k0 + ka];
            Bs[ka][n] = v;
        }
        __syncthreads();
        #pragma unroll
        for (int kk = 0; kk < BK; ++kk) {
            float a4[4], b4[4];
            #pragma unroll
            for (int i = 0; i < 4; ++i) a4[i] = As[kk][ty*4 + i];
            #pragma unroll
            for (int j = 0; j < 4; ++j) b4[j] = Bs[kk][tx*4 + j];
            #pragma unroll
            for (int i = 0; i < 4; ++i)
                #pragma unroll
                for (int j = 0; j < 4; ++j)
                    acc[i][j] += a4[i] * b4[j];
        }
        __syncthreads();
    }
    #pragma unroll
    for (int i = 0; i < 4; ++i) {
        int m = m0 + ty*4 + i;
        if (m >= M) continue;
        #pragma unroll
        for (int j = 0; j < 4; ++j) {
            int n = n0 + tx*4 + j;
            if (n >= N) continue;
            epi(m, n, acc[i][j]);
        }
    }
}

// ============================ RevIN stats ============================
__global__ __launch_bounds__(256) void revin_stats(const float* __restrict__ x,
                                                   float* __restrict__ meanb,
                                                   float* __restrict__ stdb)
{
    int b = blockIdx.x;
    int c0 = blockIdx.y * 64;
    int cl = threadIdx.x & 63;
    int sl = threadIdx.x >> 6;
    int c = c0 + cl;
    float sum = 0.f, sq = 0.f;
    if (c < CIN_) {
        for (int s = sl; s < SEQ_; s += 4) {
            float v = x[((size_t)b*SEQ_ + s)*CIN_ + c];
            sum += v; sq += v*v;
        }
    }
    __shared__ float ssum[4][64], ssq[4][64];
    ssum[sl][cl] = sum; ssq[sl][cl] = sq;
    __syncthreads();
    if (sl == 0 && c < CIN_) {
        float s = ssum[0][cl]+ssum[1][cl]+ssum[2][cl]+ssum[3][cl];
        float q = ssq[0][cl]+ssq[1][cl]+ssq[2][cl]+ssq[3][cl];
        float mn = s * (1.f/SEQ_);
        float var = q * (1.f/SEQ_) - mn*mn;
        meanb[b*CIN_ + c] = mn;
        stdb[b*CIN_ + c]  = sqrtf(var + 1e-5f);
    }
}

// ============================ normalize + transpose ============================
__global__ __launch_bounds__(256) void norm_transpose(const float* __restrict__ x,
                                                      const float* __restrict__ meanb,
                                                      const float* __restrict__ stdb,
                                                      const float* __restrict__ rw,
                                                      const float* __restrict__ rb,
                                                      float* __restrict__ xt)
{
    __shared__ float tile[64][65];
    int b = blockIdx.x, s0 = blockIdx.y*64, c0 = blockIdx.z*64;
    int cl = threadIdx.x & 63, sl = threadIdx.x >> 6;
    #pragma unroll
    for (int i = 0; i < 16; ++i) {
        int s = s0 + sl + i*4;
        int c = c0 + cl;
        float v = 0.f;
        if (c < CIN_) v = x[((size_t)b*SEQ_ + s)*CIN_ + c];
        tile[sl + i*4][cl] = v;
    }
    __syncthreads();
    int sl2 = threadIdx.x & 63, cl2 = threadIdx.x >> 6;
    #pragma unroll
    for (int i = 0; i < 16; ++i) {
        int c = c0 + cl2 + i*4;
        if (c >= CIN_) continue;
        int m = b*CIN_ + c;
        float v = tile[sl2][cl2 + i*4];
        v = (v - meanb[m]) / stdb[m] * rw[c] + rb[c];
        xt[(size_t)m*SEQ_ + s0 + sl2] = v;
    }
}

// ============================ flip tokens ============================
__global__ __launch_bounds__(256) void flip_tokens(const float* __restrict__ src,
                                                   float* __restrict__ dst)
{
    size_t i = (size_t)blockIdx.x*256 + threadIdx.x;
    int m = (int)(i / DM_), j = (int)(i % DM_);
    int b = m / L_, l = m - b*L_;
    dst[i] = src[((size_t)(b*L_ + (L_-1 - l)))*DM_ + j];
}

// ============================ depthwise causal conv + SiLU ============================
__global__ __launch_bounds__(256) void conv_silu(const float* __restrict__ xz,
                                                 const float* __restrict__ cw,
                                                 const float* __restrict__ cb,
                                                 float* __restrict__ xc, int im)
{
    int m = blockIdx.x;  // b*L_+l
    int d = blockIdx.y*256 + threadIdx.x;
    int b = m / L_, l = m - b*L_;
    float4 w = ((const float4*)cw)[(size_t)im*DI_ + d];
    float wv[4] = {w.x, w.y, w.z, w.w};
    float a = cb[im*DI_ + d];
    #pragma unroll
    for (int j = 0; j < 4; ++j) {
        int ls = l - 3 + j;
        if (ls >= 0) a += xz[((size_t)(b*L_ + ls))*(2*DI_) + d] * wv[j];
    }
    xc[(size_t)m*DI_ + d] = a * sigmoidf_(a);
}

// ============================ selective scan v2 ============================
// 256 blocks x 64 threads: one thread per (b,d); 8-step chunks, double-buffered
// register prefetch of delta/x/z streams and B/C (via regs -> LDS).
__global__ __launch_bounds__(64) void scan_kernel2(float* __restrict__ dl,
                                                   const float* __restrict__ xc,
                                                   const float* __restrict__ xz,
                                                   const float* __restrict__ dbl,
                                                   const float* __restrict__ A_log,
                                                   const float* __restrict__ Dp,
                                                   int im)
{
    const int b = blockIdx.x >> 4;
    const int lane = threadIdx.x;
    const int d = ((blockIdx.x & 15) << 6) + lane;
    float a[NST_];
    #pragma unroll
    for (int n = 0; n < NST_; ++n)
        a[n] = -__expf(A_log[((size_t)im*DI_ + d)*NST_ + n]);
    const float Dd = Dp[im*DI_ + d];
    float h[NST_] = {};
    __shared__ float sBC[2][256];
    float dv[2][8], xv[2][8], zv[2][8], bc[2][4];

    auto prefetch = [&](int tbase, int nb) {
        #pragma unroll
        for (int i = 0; i < 8; ++i) {
            int t = tbase + i;
            int tc = (t < L_) ? t : (L_-1);
            size_t base = (size_t)(b*L_ + tc);
            dv[nb][i] = dl[base*DI_ + d];
            xv[nb][i] = xc[base*DI_ + d];
            zv[nb][i] = xz[base*(size_t)(2*DI_) + DI_ + d];
        }
        #pragma unroll
        for (int i = 0; i < 4; ++i) {
            int idx = lane + (i << 6);
            int t = tbase + (idx >> 5);
            bc[nb][i] = (t < L_) ? dbl[((size_t)(b*L_ + t))*64 + 32 + (idx & 31)] : 0.f;
        }
    };

    prefetch(0, 0);
    int buf = 0;
    for (int t0 = 0; t0 < L_; t0 += 8, buf ^= 1) {
        if (t0 + 8 < L_) prefetch(t0 + 8, buf ^ 1);
        #pragma unroll
        for (int i = 0; i < 4; ++i) sBC[buf][lane + (i << 6)] = bc[buf][i];
        __syncthreads();
        #pragma unroll
        for (int i = 0; i < 8; ++i) {
            int t = t0 + i;
            if (t < L_) {
                float dvv = dv[buf][i], xvv = xv[buf][i], zvv = zv[buf][i];
                float du = dvv * xvv;
                float y = 0.f;
                const float* bcp = &sBC[buf][i*32];
                #pragma unroll
                for (int n = 0; n < NST_; ++n) {
                    float dA = __expf(dvv * a[n]);
                    h[n] = dA*h[n] + du*bcp[n];
                    y += h[n]*bcp[16+n];
                }
                y = (y + Dd*xvv) * (zvv * sigmoidf_(zvv));
                dl[((size_t)(b*L_ + t))*DI_ + d] = y;
            }
        }
        __syncthreads();
    }
}

// ============================ launch ============================
extern "C" void kernel_launch(void* const* d_in, const int* in_sizes, int n_in,
                              void* d_out, int out_size, void* d_ws, size_t ws_size,
                              hipStream_t stream)
{
    const float* x      = (const float*)d_in[0];
    const float* rw     = (const float*)d_in[1];
    const float* rb     = (const float*)d_in[2];
    const float* lin1_w = (const float*)d_in[3];
    const float* lin1_b = (const float*)d_in[4];
    const float* head_w = (const float*)d_in[5];
    const float* head_b = (const float*)d_in[6];
    const float* ipw    = (const float*)d_in[7];
    const float* cw     = (const float*)d_in[8];
    const float* cb     = (const float*)d_in[9];
    const float* xpw    = (const float*)d_in[10];
    const float* dpw    = (const float*)d_in[11];
    const float* dpb    = (const float*)d_in[12];
    const float* A_log  = (const float*)d_in[13];
    const float* Dp     = (const float*)d_in[14];
    const float* opw    = (const float*)d_in[15];
    float* out = (float*)d_out;

    float* ws = (float*)d_ws;
    size_t off = 0;
    auto alloc = [&](size_t n) { float* p = ws + off; off += (n + 63) & ~(size_t)63; return p; };
    float* meanb = alloc(NT_);
    float* stdb  = alloc(NT_);
    float* xnt   = alloc((size_t)NT_*SEQ_);      // also reused as flipped-t buffer
    float* tb0   = alloc((size_t)NT_*DM_);
    float* tb1   = alloc((size_t)NT_*DM_);
    float* xz    = alloc((size_t)NT_*2*DI_);
    float* xc    = alloc((size_t)NT_*DI_);
    float* dl    = alloc((size_t)NT_*DI_);       // delta, then gated y (in place)
    float* dblb  = alloc((size_t)NT_*64);
    (void)ws_size; (void)in_sizes; (void)n_in; (void)out_size;

    dim3 blk(256);
    const int MT64  = (NT_ + 63) / 64;    // 81
    const int MT128 = (NT_ + 127) / 128;  // 41

    revin_stats<<<dim3(B_, 6), blk, 0, stream>>>(x, meanb, stdb);
    norm_transpose<<<dim3(B_, 8, 6), blk, 0, stream>>>(x, meanb, stdb, rw, rb, xnt);
    gemm_mfma<<<dim3(MT128, DM_/128), blk, 0, stream>>>(xnt, SEQ_, lin1_w, SEQ_, NT_, DM_, SEQ_,
                                                        EpiBias{tb0, DM_, lin1_b});

    float* tin = tb0; float* tout = tb1;
    for (int layer = 0; layer < 2; ++layer) {
        hipMemcpyAsync(tout, tin, (size_t)NT_*DM_*sizeof(float), hipMemcpyDeviceToDevice, stream);
        for (int dir = 0; dir < 2; ++dir) {
            const int im = dir;
            const float* Ain = tin;
            if (dir == 1) {
                flip_tokens<<<dim3((NT_*DM_)/256), blk, 0, stream>>>(tin, xnt);
                Ain = xnt;
            }
            // in_proj: (NT, 2*DI) = Ain(NT,DM) @ ipw[im]^T   [bf16 MFMA]
            gemm_mfma<<<dim3(MT128, (2*DI_)/128), blk, 0, stream>>>(Ain, DM_, ipw + (size_t)im*2*DI_*DM_, DM_,
                                                                    NT_, 2*DI_, DM_, EpiStore{xz, 2*DI_});
            conv_silu<<<dim3(NT_, DI_/256), blk, 0, stream>>>(xz, cw, cb, xc, im);
            // x_proj: (NT, 64) = xc @ xpw[im]^T   [fp32 — feeds dt/B/C]
            gemm_tn<<<dim3(MT64, 1), blk, 0, stream>>>(xc, DI_, xpw + (size_t)im*64*DI_, DI_,
                                                       NT_, 64, DI_, EpiStore{dblb, 64});
            // delta: softplus(dt @ dpw[im]^T + dpb[im])   [fp32 — exp-sensitive]
            gemm_tn<<<dim3(MT64, DI_/64), blk, 0, stream>>>(dblb, 64, dpw + (size_t)im*DI_*RNK_, RNK_,
                                                            NT_, DI_, RNK_,
                                                            EpiSoftplusBias{dl, DI_, dpb + im*DI_});
            scan_kernel2<<<dim3(256), dim3(64), 0, stream>>>(dl, xc, xz, dblb, A_log, Dp, im);
            // out_proj accumulate into tout (flipped rows for dir=1)   [bf16 MFMA]
            gemm_mfma<<<dim3(MT128, DM_/128), blk, 0, stream>>>(dl, DI_, opw + (size_t)im*DM_*DI_, DI_,
                                                                NT_, DM_, DI_, EpiAccFlip{tout, DM_, dir});
        }
        float* tmp = tin; tin = tout; tout = tmp;
    }
    gemm_mfma<<<dim3(MT128, 1), blk, 0, stream>>>(tin, DM_, head_w, DM_, NT_, PRED_, DM_,
                                                  EpiHead{out, head_b, meanb, stdb, rw, rb});
}

// Round 3
// 2504.652 us; speedup vs baseline: 1.5805x; 1.0519x over previous
//
#include <hip/hip_runtime.h>
#include <hip/hip_bf16.h>
#include <cstdint>
#include <cstddef>

#define B_    16
#define SEQ_  512
#define CIN_  321
#define PRED_ 96
#define DM_   512
#define DI_   1024
#define NST_  16
#define RNK_  32
#define L_    321
#define NT_   (B_*CIN_)   // 5136 tokens
#define PADM_ 5248        // NT_ padded up to multiple of 128 for OOB-safe tile reads

typedef unsigned short ushort_t;
typedef __bf16 bf16x8 __attribute__((ext_vector_type(8)));
typedef float  f32x4  __attribute__((ext_vector_type(4)));
typedef __attribute__((address_space(3))) void lds_void_t;
typedef const __attribute__((address_space(1))) void gbl_void_t;

__device__ __forceinline__ float sigmoidf_(float x){ return 1.f/(1.f+__expf(-x)); }
__device__ __forceinline__ float softplusf_(float x){ return (x>20.f) ? x : log1pf(__expf(x)); }
__device__ __forceinline__ ushort_t f2bf(float f){
    union { float f; unsigned u; } v; v.f = f;
    unsigned r = v.u + 0x7FFF + ((v.u >> 16) & 1);
    return (ushort_t)(r >> 16);
}

// ============================ epilogues ============================
struct EpiStoreF {            // fp32 store, optional token flip (bwd branch)
    float* C; int ldc; int flip;
    __device__ void operator()(int m, int n, float v) const {
        int mm = m;
        if (flip) { int b = m / L_; int l = m - b*L_; mm = b*L_ + (L_-1 - l); }
        C[(size_t)mm*ldc + n] = v;
    }
};
struct EpiBiasDual {          // fp32 + bf16 copy (embed -> residual + GEMM input)
    float* C; ushort_t* Cb; int ldc; const float* bias;
    __device__ void operator()(int m, int n, float v) const {
        float o = v + bias[n];
        C[(size_t)m*ldc + n] = o;
        Cb[(size_t)m*ldc + n] = f2bf(o);
    }
};
struct EpiSoftplusBias {
    float* C; int ldc; const float* bias;
    __device__ void operator()(int m, int n, float v) const {
        C[(size_t)m*ldc + n] = softplusf_(v + bias[n]);
    }
};
struct EpiAccFlip {
    float* C; int ldc; int flip;
    __device__ void operator()(int m, int n, float v) const {
        int mm = m;
        if (flip) { int b = m / L_; int l = m - b*L_; mm = b*L_ + (L_-1 - l); }
        C[(size_t)mm*ldc + n] += v;
    }
};
struct EpiStore32 {
    float* C; int ldc;
    __device__ void operator()(int m, int n, float v) const { C[(size_t)m*ldc + n] = v; }
};
struct EpiHead {
    float* out; const float* bias; const float* mean; const float* stdv;
    const float* rw; const float* rb;
    __device__ void operator()(int m, int n, float v) const {
        int b = m / CIN_, c = m - b*CIN_;
        float o = v + bias[n];
        o = (o - rb[c]) / (rw[c] + 1e-10f);
        o = o * stdv[m] + mean[m];
        out[((size_t)b*PRED_ + n)*CIN_ + c] = o;
    }
};

// ============================ bf16 MFMA GEMM (TN), m97-style staging ============================
// C[m,n] = sum_k A[m*lda+k]*Bw[n*ldb+k], bf16 inputs, fp32 acc.
// K%32==0. A must be readable up to row ceil128(M)-1 (padded alloc). N rows of Bw
// readable up to ceil128(N)-1. LDS As[128][32] unpadded: conflict-free for both
// global_load_lds (lane-linear) and ds_read_b128 frag reads (8 lanes/bank-quad, 8 phases).
template<typename Epi>
__global__ __launch_bounds__(256) void gemm_bf16(const ushort_t* __restrict__ A, int lda,
                                                 const ushort_t* __restrict__ Bw, int ldb,
                                                 int M, int N, int K, Epi epi)
{
    __shared__ __align__(16) ushort_t As[128*32];
    __shared__ __align__(16) ushort_t Bs[128*32];
    const int tid  = threadIdx.x;
    const int m0 = blockIdx.x * 128, n0 = blockIdx.y * 128;
    const int wave = tid >> 6, lane = tid & 63;
    const int wm = (wave & 1) * 64, wn = (wave >> 1) * 64;
    const int ln16 = lane & 15, quad = lane >> 4;
    const int srow = lane >> 2, scol = (lane & 3) * 8;   // staging: 16 rows x 32 k per wave-inst

    const ushort_t* Ag = A + (size_t)(m0 + wave*32 + srow)*lda + scol;
    const ushort_t* Bg = Bw + (size_t)(n0 + wave*32 + srow)*ldb + scol;
    ushort_t* AsW = As + wave*32*32;
    ushort_t* BsW = Bs + wave*32*32;

    f32x4 acc[4][4] = {};
    for (int k0 = 0; k0 < K; k0 += 32) {
        __builtin_amdgcn_global_load_lds((gbl_void_t*)(Ag + k0),             (lds_void_t*)AsW,            16, 0, 0);
        __builtin_amdgcn_global_load_lds((gbl_void_t*)(Ag + k0 + 16*(size_t)lda), (lds_void_t*)(AsW + 16*32), 16, 0, 0);
        __builtin_amdgcn_global_load_lds((gbl_void_t*)(Bg + k0),             (lds_void_t*)BsW,            16, 0, 0);
        __builtin_amdgcn_global_load_lds((gbl_void_t*)(Bg + k0 + 16*(size_t)ldb), (lds_void_t*)(BsW + 16*32), 16, 0, 0);
        __syncthreads();
        bf16x8 af[4], bfr[4];
        #pragma unroll
        for (int i = 0; i < 4; ++i)
            af[i] = *(const bf16x8*)(As + (wm + i*16 + ln16)*32 + quad*8);
        #pragma unroll
        for (int i = 0; i < 4; ++i)
            bfr[i] = *(const bf16x8*)(Bs + (wn + i*16 + ln16)*32 + quad*8);
        #pragma unroll
        for (int mi = 0; mi < 4; ++mi)
            #pragma unroll
            for (int ni = 0; ni < 4; ++ni)
                acc[mi][ni] = __builtin_amdgcn_mfma_f32_16x16x32_bf16(af[mi], bfr[ni], acc[mi][ni], 0, 0, 0);
        __syncthreads();
    }
    #pragma unroll
    for (int mi = 0; mi < 4; ++mi) {
        #pragma unroll
        for (int r = 0; r < 4; ++r) {
            int m = m0 + wm + mi*16 + quad*4 + r;
            if (m >= M) continue;
            #pragma unroll
            for (int ni = 0; ni < 4; ++ni) {
                int n = n0 + wn + ni*16 + ln16;
                if (n < N) epi(m, n, acc[mi][ni][r]);
            }
        }
    }
}

// ============================ fp32 GEMM (TN) — small, precision-sensitive matmuls ============================
template<typename Epi>
__global__ __launch_bounds__(256) void gemm_tn(const float* __restrict__ A, int lda,
                                               const float* __restrict__ Bw, int ldb,
                                               int M, int N, int K, Epi epi)
{
    constexpr int BM = 64, BN = 64, BK = 32;
    __shared__ __align__(16) float As[BK][BM+4];
    __shared__ __align__(16) float Bs[BK][BN+4];
    const int tid = threadIdx.x;
    const int m0 = blockIdx.x * BM;
    const int n0 = blockIdx.y * BN;
    const int tx = tid & 15, ty = tid >> 4;
    const int ka = tid & (BK-1);
    const int ra = tid >> 5;

    float acc[4][4] = {};
    for (int k0 = 0; k0 < K; k0 += BK) {
        #pragma unroll
        for (int i = 0; i < 8; ++i) {
            int m = ra + i*8;
            int gm = m0 + m;
            float v = 0.f;
            if (gm < M) v = A[(size_t)gm*lda + k0 + ka];
            As[ka][m] = v;
        }
        #pragma unroll
        for (int i = 0; i < 8; ++i) {
            int n = ra + i*8;
            int gn = n0 + n;
            float v = 0.f;
            if (gn < N) v = Bw[(size_t)gn*ldb + k0 + ka];
            Bs[ka][n] = v;
        }
        __syncthreads();
        #pragma unroll
        for (int kk = 0; kk < BK; ++kk) {
            float a4[4], b4[4];
            #pragma unroll
            for (int i = 0; i < 4; ++i) a4[i] = As[kk][ty*4 + i];
            #pragma unroll
            for (int j = 0; j < 4; ++j) b4[j] = Bs[kk][tx*4 + j];
            #pragma unroll
            for (int i = 0; i < 4; ++i)
                #pragma unroll
                for (int j = 0; j < 4; ++j)
                    acc[i][j] += a4[i] * b4[j];
        }
        __syncthreads();
    }
    #pragma unroll
    for (int i = 0; i < 4; ++i) {
        int m = m0 + ty*4 + i;
        if (m >= M) continue;
        #pragma unroll
        for (int j = 0; j < 4; ++j) {
            int n = n0 + tx*4 + j;
            if (n >= N) continue;
            epi(m, n, acc[i][j]);
        }
    }
}

// ============================ fp32 -> bf16 convert ============================
__global__ __launch_bounds__(256) void f32_to_bf16v(const float4* __restrict__ s,
                                                    ushort4* __restrict__ d, int n4)
{
    int i = blockIdx.x*256 + threadIdx.x;
    if (i < n4) {
        float4 v = s[i];
        ushort4 u; u.x=f2bf(v.x); u.y=f2bf(v.y); u.z=f2bf(v.z); u.w=f2bf(v.w);
        d[i] = u;
    }
}

// ============================ RevIN stats ============================
__global__ __launch_bounds__(256) void revin_stats(const float* __restrict__ x,
                                                   float* __restrict__ meanb,
                                                   float* __restrict__ stdb)
{
    int b = blockIdx.x;
    int c0 = blockIdx.y * 64;
    int cl = threadIdx.x & 63;
    int sl = threadIdx.x >> 6;
    int c = c0 + cl;
    float sum = 0.f, sq = 0.f;
    if (c < CIN_) {
        for (int s = sl; s < SEQ_; s += 4) {
            float v = x[((size_t)b*SEQ_ + s)*CIN_ + c];
            sum += v; sq += v*v;
        }
    }
    __shared__ float ssum[4][64], ssq[4][64];
    ssum[sl][cl] = sum; ssq[sl][cl] = sq;
    __syncthreads();
    if (sl == 0 && c < CIN_) {
        float s = ssum[0][cl]+ssum[1][cl]+ssum[2][cl]+ssum[3][cl];
        float q = ssq[0][cl]+ssq[1][cl]+ssq[2][cl]+ssq[3][cl];
        float mn = s * (1.f/SEQ_);
        float var = q * (1.f/SEQ_) - mn*mn;
        meanb[b*CIN_ + c] = mn;
        stdb[b*CIN_ + c]  = sqrtf(var + 1e-5f);
    }
}

// ============================ normalize + transpose (writes bf16) ============================
__global__ __launch_bounds__(256) void norm_transpose(const float* __restrict__ x,
                                                      const float* __restrict__ meanb,
                                                      const float* __restrict__ stdb,
                                                      const float* __restrict__ rw,
                                                      const float* __restrict__ rb,
                                                      ushort_t* __restrict__ xt)
{
    __shared__ float tile[64][65];
    int b = blockIdx.x, s0 = blockIdx.y*64, c0 = blockIdx.z*64;
    int cl = threadIdx.x & 63, sl = threadIdx.x >> 6;
    #pragma unroll
    for (int i = 0; i < 16; ++i) {
        int s = s0 + sl + i*4;
        int c = c0 + cl;
        float v = 0.f;
        if (c < CIN_) v = x[((size_t)b*SEQ_ + s)*CIN_ + c];
        tile[sl + i*4][cl] = v;
    }
    __syncthreads();
    int sl2 = threadIdx.x & 63, cl2 = threadIdx.x >> 6;
    #pragma unroll
    for (int i = 0; i < 16; ++i) {
        int c = c0 + cl2 + i*4;
        if (c >= CIN_) continue;
        int m = b*CIN_ + c;
        float v = tile[sl2][cl2 + i*4];
        v = (v - meanb[m]) / stdb[m] * rw[c] + rb[c];
        xt[(size_t)m*SEQ_ + s0 + sl2] = f2bf(v);
    }
}

// ============================ depthwise causal conv + SiLU ============================
__global__ __launch_bounds__(256) void conv_silu(const float* __restrict__ xz,
                                                 const float* __restrict__ cw,
                                                 const float* __restrict__ cb,
                                                 float* __restrict__ xc, int im)
{
    int m = blockIdx.x;  // b*L_+l
    int d = blockIdx.y*256 + threadIdx.x;
    int b = m / L_, l = m - b*L_;
    float4 w = ((const float4*)cw)[(size_t)im*DI_ + d];
    float wv[4] = {w.x, w.y, w.z, w.w};
    float a = cb[im*DI_ + d];
    #pragma unroll
    for (int j = 0; j < 4; ++j) {
        int ls = l - 3 + j;
        if (ls >= 0) a += xz[((size_t)(b*L_ + ls))*(2*DI_) + d] * wv[j];
    }
    xc[(size_t)m*DI_ + d] = a * sigmoidf_(a);
}

// ============================ selective scan v3 (barrier-free, 1 wave/block) ============================
// 256 blocks x 64 threads: thread = (b, d). 8-step chunks, register double-buffered
// prefetch; B/C staged regs->LDS, read wave-synchronously (no __syncthreads =>
// no vmcnt(0) drain, prefetch stays in flight). Writes gated y as bf16 into the
// consumed x-half of xz (token stride 4096 ushorts) for out_proj to read.
__global__ __launch_bounds__(64) void scan_v3(const float* __restrict__ dl,
                                              const float* __restrict__ xc,
                                              float* __restrict__ xz,
                                              const float* __restrict__ dbl,
                                              const float* __restrict__ A_log,
                                              const float* __restrict__ Dp, int im)
{
    const int b = blockIdx.x >> 4;
    const int lane = threadIdx.x;
    const int d = ((blockIdx.x & 15) << 6) + lane;
    float a[NST_];
    #pragma unroll
    for (int n = 0; n < NST_; ++n)
        a[n] = -__expf(A_log[((size_t)im*DI_ + d)*NST_ + n]);
    const float Dd = Dp[im*DI_ + d];
    float h[NST_] = {};
    __shared__ float sBC[2][256];
    float dv[2][8], xv[2][8], zv[2][8], bc[2][4];
    ushort_t* yb = (ushort_t*)xz;

    auto prefetch = [&](int tbase, int nb) {
        #pragma unroll
        for (int i = 0; i < 8; ++i) {
            int t = tbase + i; int tc = (t < L_) ? t : (L_-1);
            size_t rtok = (size_t)(b*L_ + tc);
            dv[nb][i] = dl[rtok*DI_ + d];
            xv[nb][i] = xc[rtok*DI_ + d];
            zv[nb][i] = xz[rtok*2*DI_ + DI_ + d];
        }
        #pragma unroll
        for (int i = 0; i < 4; ++i) {
            int idx = lane + (i << 6);
            int t = tbase + (idx >> 5);
            int tc = (t < L_) ? t : (L_-1);
            bc[nb][i] = dbl[((size_t)(b*L_ + tc))*64 + 32 + (idx & 31)];
        }
    };

    prefetch(0, 0);
    #pragma unroll
    for (int i = 0; i < 4; ++i) sBC[0][lane + (i<<6)] = bc[0][i];

    int buf = 0;
    for (int t0 = 0; t0 < L_; t0 += 8, buf ^= 1) {
        const int nb = buf ^ 1;
        if (t0 + 8 < L_) prefetch(t0 + 8, nb);
        #pragma unroll
        for (int i = 0; i < 8; ++i) {
            int t = t0 + i;
            if (t < L_) {
                float dvv = dv[buf][i], xvv = xv[buf][i], zvv = zv[buf][i];
                float du = dvv * xvv;
                float y = 0.f;
                const float* bcp = &sBC[buf][i*32];
                #pragma unroll
                for (int n = 0; n < NST_; ++n) {
                    float dA = __expf(dvv * a[n]);
                    h[n] = dA*h[n] + du*bcp[n];
                    y += h[n]*bcp[16+n];
                }
                y = (y + Dd*xvv) * (zvv * sigmoidf_(zvv));
                yb[((size_t)(b*L_ + t))*4096 + d] = f2bf(y);
            }
        }
        if (t0 + 8 < L_) {
            #pragma unroll
            for (int i = 0; i < 4; ++i) sBC[nb][lane + (i<<6)] = bc[nb][i];
        }
    }
}

// ============================ launch ============================
extern "C" void kernel_launch(void* const* d_in, const int* in_sizes, int n_in,
                              void* d_out, int out_size, void* d_ws, size_t ws_size,
                              hipStream_t stream)
{
    const float* x      = (const float*)d_in[0];
    const float* rw     = (const float*)d_in[1];
    const float* rb     = (const float*)d_in[2];
    const float* lin1_w = (const float*)d_in[3];
    const float* lin1_b = (const float*)d_in[4];
    const float* head_w = (const float*)d_in[5];
    const float* head_b = (const float*)d_in[6];
    const float* ipw    = (const float*)d_in[7];
    const float* cw     = (const float*)d_in[8];
    const float* cb     = (const float*)d_in[9];
    const float* xpw    = (const float*)d_in[10];
    const float* dpw    = (const float*)d_in[11];
    const float* dpb    = (const float*)d_in[12];
    const float* A_log  = (const float*)d_in[13];
    const float* Dp     = (const float*)d_in[14];
    const float* opw    = (const float*)d_in[15];
    float* out = (float*)d_out;

    float* ws = (float*)d_ws;
    size_t off = 0;
    auto alloc = [&](size_t nfloats) { float* p = ws + off; off += (nfloats + 63) & ~(size_t)63; return p; };
    float* meanb = alloc(NT_);
    float* stdb  = alloc(NT_);
    ushort_t* xnt_bf = (ushort_t*)alloc((size_t)PADM_*DM_/2);
    ushort_t* tbf    = (ushort_t*)alloc((size_t)PADM_*DM_/2);
    float* tb0   = alloc((size_t)NT_*DM_);
    float* tb1   = alloc((size_t)NT_*DM_);
    float* xz    = alloc((size_t)PADM_*2*DI_);   // padded: out_proj reads ybf rows to PADM_-1
    float* xc    = alloc((size_t)NT_*DI_);
    float* dl    = alloc((size_t)NT_*DI_);
    float* dblb  = alloc((size_t)NT_*64);
    ushort_t* lin1_bf = (ushort_t*)alloc((size_t)DM_*SEQ_/2);
    ushort_t* head_bf = (ushort_t*)alloc((size_t)128*DM_/2);   // padded 96->128 rows
    ushort_t* ipw_bf  = (ushort_t*)alloc((size_t)2*2*DI_*DM_/2);
    ushort_t* opw_bf  = (ushort_t*)alloc((size_t)2*DM_*DI_/2);
    (void)ws_size; (void)in_sizes; (void)n_in; (void)out_size;

    dim3 blk(256);
    const int MT64  = (NT_ + 63) / 64;     // 81
    const int MT128 = (NT_ + 127) / 128;   // 41
    auto cvt = [&](const float* s, ushort_t* d, int n) {
        int n4 = n / 4;
        f32_to_bf16v<<<dim3((n4+255)/256), blk, 0, stream>>>((const float4*)s, (ushort4*)d, n4);
    };

    // one-time weight conversion (per launch; ~6 us total)
    cvt(lin1_w, lin1_bf, DM_*SEQ_);
    cvt(head_w, head_bf, PRED_*DM_);
    cvt(ipw,    ipw_bf,  2*2*DI_*DM_);
    cvt(opw,    opw_bf,  2*DM_*DI_);

    revin_stats<<<dim3(B_, 6), blk, 0, stream>>>(x, meanb, stdb);
    norm_transpose<<<dim3(B_, 8, 6), blk, 0, stream>>>(x, meanb, stdb, rw, rb, xnt_bf);
    gemm_bf16<<<dim3(MT128, DM_/128), blk, 0, stream>>>(xnt_bf, SEQ_, lin1_bf, SEQ_,
                                                        NT_, DM_, SEQ_,
                                                        EpiBiasDual{tb0, tbf, DM_, lin1_b});

    float* tin = tb0; float* tout = tb1;
    for (int layer = 0; layer < 2; ++layer) {
        hipMemcpyAsync(tout, tin, (size_t)NT_*DM_*sizeof(float), hipMemcpyDeviceToDevice, stream);
        for (int dir = 0; dir < 2; ++dir) {
            const int im = dir;
            // in_proj: xz = t @ ipw[im]^T  (dir=1: rows written flipped => bwd token order)
            gemm_bf16<<<dim3(MT128, (2*DI_)/128), blk, 0, stream>>>(
                tbf, DM_, ipw_bf + (size_t)im*2*DI_*DM_, DM_,
                NT_, 2*DI_, DM_, EpiStoreF{xz, 2*DI_, dir});
            conv_silu<<<dim3(NT_, DI_/256), blk, 0, stream>>>(xz, cw, cb, xc, im);
            // x_proj (fp32, feeds dt/B/C)
            gemm_tn<<<dim3(MT64, 1), blk, 0, stream>>>(xc, DI_, xpw + (size_t)im*64*DI_, DI_,
                                                       NT_, 64, DI_, EpiStore32{dblb, 64});
            // delta = softplus(dt @ dpw^T + dpb)  (fp32, exp-sensitive)
            gemm_tn<<<dim3(MT64, DI_/64), blk, 0, stream>>>(dblb, 64, dpw + (size_t)im*DI_*RNK_, RNK_,
                                                            NT_, DI_, RNK_,
                                                            EpiSoftplusBias{dl, DI_, dpb + im*DI_});
            scan_v3<<<dim3(256), dim3(64), 0, stream>>>(dl, xc, xz, dblb, A_log, Dp, im);
            // out_proj: tout += y @ opw[im]^T  (dir=1: rows accumulated flipped back)
            gemm_bf16<<<dim3(MT128, DM_/128), blk, 0, stream>>>(
                (const ushort_t*)xz, 4*DI_, opw_bf + (size_t)im*DM_*DI_, DI_,
                NT_, DM_, DI_, EpiAccFlip{tout, DM_, dir});
        }
        float* tmp = tin; tin = tout; tout = tmp;
        cvt(tin, tbf, NT_*DM_);   // bf16 copy for next layer's in_proj / final head
    }
    gemm_bf16<<<dim3(MT128, 1), blk, 0, stream>>>(tbf, DM_, head_bf, DM_, NT_, PRED_, DM_,
                                                  EpiHead{out, head_b, meanb, stdb, rw, rb});
}

// Round 4
// 1627.229 us; speedup vs baseline: 2.4327x; 1.5392x over previous
//
#include <hip/hip_runtime.h>
#include <hip/hip_bf16.h>
#include <cstdint>
#include <cstddef>

#define B_    16
#define SEQ_  512
#define CIN_  321
#define PRED_ 96
#define DM_   512
#define DI_   1024
#define NST_  16
#define RNK_  32
#define L_    321
#define NT_   (B_*CIN_)   // 5136 tokens
#define PADM_ 5248        // NT_ padded to multiple of 128 for OOB-safe tile reads

typedef unsigned short ushort_t;
typedef __bf16 bf16x8 __attribute__((ext_vector_type(8)));
typedef float  f32x4  __attribute__((ext_vector_type(4)));
typedef __attribute__((address_space(3))) void lds_void_t;
typedef const __attribute__((address_space(1))) void gbl_void_t;

__device__ __forceinline__ float sigmoidf_(float x){ return 1.f/(1.f+__expf(-x)); }
__device__ __forceinline__ float softplusf_(float x){ return (x>20.f) ? x : log1pf(__expf(x)); }
__device__ __forceinline__ ushort_t f2bf(float f){
    union { float f; unsigned u; } v; v.f = f;
    unsigned r = v.u + 0x7FFF + ((v.u >> 16) & 1);
    return (ushort_t)(r >> 16);
}

// ============================ epilogues ============================
struct EpiStoreF {            // fp32 store, optional token flip (bwd branch)
    float* C; int ldc; int flip;
    __device__ void operator()(int m, int n, float v) const {
        int mm = m;
        if (flip) { int b = m / L_; int l = m - b*L_; mm = b*L_ + (L_-1 - l); }
        C[(size_t)mm*ldc + n] = v;
    }
};
struct EpiBiasDual {          // fp32 + bf16 copy (embed -> residual + GEMM input)
    float* C; ushort_t* Cb; int ldc; const float* bias;
    __device__ void operator()(int m, int n, float v) const {
        float o = v + bias[n];
        C[(size_t)m*ldc + n] = o;
        Cb[(size_t)m*ldc + n] = f2bf(o);
    }
};
struct EpiSoftplusBias {
    float* C; int ldc; const float* bias;
    __device__ void operator()(int m, int n, float v) const {
        C[(size_t)m*ldc + n] = softplusf_(v + bias[n]);
    }
};
struct EpiAcc {               // fwd out_proj: accumulate into residual
    float* C; int ldc;
    __device__ void operator()(int m, int n, float v) const {
        C[(size_t)m*ldc + n] += v;
    }
};
struct EpiAccFlipDual {       // bwd out_proj: accumulate flipped + bf16 copy of final residual
    float* C; ushort_t* Cb; int ldc;
    __device__ void operator()(int m, int n, float v) const {
        int b = m / L_; int l = m - b*L_; int mm = b*L_ + (L_-1 - l);
        float o = C[(size_t)mm*ldc + n] + v;
        C[(size_t)mm*ldc + n] = o;
        Cb[(size_t)mm*ldc + n] = f2bf(o);
    }
};
struct EpiStore32 {
    float* C; int ldc;
    __device__ void operator()(int m, int n, float v) const { C[(size_t)m*ldc + n] = v; }
};
struct EpiHead {
    float* out; const float* bias; const float* mean; const float* stdv;
    const float* rw; const float* rb;
    __device__ void operator()(int m, int n, float v) const {
        int b = m / CIN_, c = m - b*CIN_;
        float o = v + bias[n];
        o = (o - rb[c]) / (rw[c] + 1e-10f);
        o = o * stdv[m] + mean[m];
        out[((size_t)b*PRED_ + n)*CIN_ + c] = o;
    }
};

// ============================ bf16 MFMA GEMM (TN), m97-style staging ============================
template<typename Epi>
__global__ __launch_bounds__(256) void gemm_bf16(const ushort_t* __restrict__ A, int lda,
                                                 const ushort_t* __restrict__ Bw, int ldb,
                                                 int M, int N, int K, Epi epi)
{
    __shared__ __align__(16) ushort_t As[128*32];
    __shared__ __align__(16) ushort_t Bs[128*32];
    const int tid  = threadIdx.x;
    const int m0 = blockIdx.x * 128, n0 = blockIdx.y * 128;
    const int wave = tid >> 6, lane = tid & 63;
    const int wm = (wave & 1) * 64, wn = (wave >> 1) * 64;
    const int ln16 = lane & 15, quad = lane >> 4;
    const int srow = lane >> 2, scol = (lane & 3) * 8;

    const ushort_t* Ag = A + (size_t)(m0 + wave*32 + srow)*lda + scol;
    const ushort_t* Bg = Bw + (size_t)(n0 + wave*32 + srow)*ldb + scol;
    ushort_t* AsW = As + wave*32*32;
    ushort_t* BsW = Bs + wave*32*32;

    f32x4 acc[4][4] = {};
    for (int k0 = 0; k0 < K; k0 += 32) {
        __builtin_amdgcn_global_load_lds((gbl_void_t*)(Ag + k0),                  (lds_void_t*)AsW,           16, 0, 0);
        __builtin_amdgcn_global_load_lds((gbl_void_t*)(Ag + k0 + 16*(size_t)lda), (lds_void_t*)(AsW + 16*32), 16, 0, 0);
        __builtin_amdgcn_global_load_lds((gbl_void_t*)(Bg + k0),                  (lds_void_t*)BsW,           16, 0, 0);
        __builtin_amdgcn_global_load_lds((gbl_void_t*)(Bg + k0 + 16*(size_t)ldb), (lds_void_t*)(BsW + 16*32), 16, 0, 0);
        __syncthreads();
        bf16x8 af[4], bfr[4];
        #pragma unroll
        for (int i = 0; i < 4; ++i)
            af[i] = *(const bf16x8*)(As + (wm + i*16 + ln16)*32 + quad*8);
        #pragma unroll
        for (int i = 0; i < 4; ++i)
            bfr[i] = *(const bf16x8*)(Bs + (wn + i*16 + ln16)*32 + quad*8);
        #pragma unroll
        for (int mi = 0; mi < 4; ++mi)
            #pragma unroll
            for (int ni = 0; ni < 4; ++ni)
                acc[mi][ni] = __builtin_amdgcn_mfma_f32_16x16x32_bf16(af[mi], bfr[ni], acc[mi][ni], 0, 0, 0);
        __syncthreads();
    }
    #pragma unroll
    for (int mi = 0; mi < 4; ++mi) {
        #pragma unroll
        for (int r = 0; r < 4; ++r) {
            int m = m0 + wm + mi*16 + quad*4 + r;
            if (m >= M) continue;
            #pragma unroll
            for (int ni = 0; ni < 4; ++ni) {
                int n = n0 + wn + ni*16 + ln16;
                if (n < N) epi(m, n, acc[mi][ni][r]);
            }
        }
    }
}

// ============================ fp32 GEMM (TN) — precision-sensitive dt matmul ============================
template<typename Epi>
__global__ __launch_bounds__(256) void gemm_tn(const float* __restrict__ A, int lda,
                                               const float* __restrict__ Bw, int ldb,
                                               int M, int N, int K, Epi epi)
{
    constexpr int BM = 64, BN = 64, BK = 32;
    __shared__ __align__(16) float As[BK][BM+4];
    __shared__ __align__(16) float Bs[BK][BN+4];
    const int tid = threadIdx.x;
    const int m0 = blockIdx.x * BM;
    const int n0 = blockIdx.y * BN;
    const int tx = tid & 15, ty = tid >> 4;
    const int ka = tid & (BK-1);
    const int ra = tid >> 5;

    float acc[4][4] = {};
    for (int k0 = 0; k0 < K; k0 += BK) {
        #pragma unroll
        for (int i = 0; i < 8; ++i) {
            int m = ra + i*8;
            int gm = m0 + m;
            float v = 0.f;
            if (gm < M) v = A[(size_t)gm*lda + k0 + ka];
            As[ka][m] = v;
        }
        #pragma unroll
        for (int i = 0; i < 8; ++i) {
            int n = ra + i*8;
            int gn = n0 + n;
            float v = 0.f;
            if (gn < N) v = Bw[(size_t)gn*ldb + k0 + ka];
            Bs[ka][n] = v;
        }
        __syncthreads();
        #pragma unroll
        for (int kk = 0; kk < BK; ++kk) {
            float a4[4], b4[4];
            #pragma unroll
            for (int i = 0; i < 4; ++i) a4[i] = As[kk][ty*4 + i];
            #pragma unroll
            for (int j = 0; j < 4; ++j) b4[j] = Bs[kk][tx*4 + j];
            #pragma unroll
            for (int i = 0; i < 4; ++i)
                #pragma unroll
                for (int j = 0; j < 4; ++j)
                    acc[i][j] += a4[i] * b4[j];
        }
        __syncthreads();
    }
    #pragma unroll
    for (int i = 0; i < 4; ++i) {
        int m = m0 + ty*4 + i;
        if (m >= M) continue;
        #pragma unroll
        for (int j = 0; j < 4; ++j) {
            int n = n0 + tx*4 + j;
            if (n >= N) continue;
            epi(m, n, acc[i][j]);
        }
    }
}

// ============================ fp32 -> bf16 convert ============================
__global__ __launch_bounds__(256) void f32_to_bf16v(const float4* __restrict__ s,
                                                    ushort4* __restrict__ d, int n4)
{
    int i = blockIdx.x*256 + threadIdx.x;
    if (i < n4) {
        float4 v = s[i];
        ushort4 u; u.x=f2bf(v.x); u.y=f2bf(v.y); u.z=f2bf(v.z); u.w=f2bf(v.w);
        d[i] = u;
    }
}

// ============================ RevIN stats ============================
__global__ __launch_bounds__(256) void revin_stats(const float* __restrict__ x,
                                                   float* __restrict__ meanb,
                                                   float* __restrict__ stdb)
{
    int b = blockIdx.x;
    int c0 = blockIdx.y * 64;
    int cl = threadIdx.x & 63;
    int sl = threadIdx.x >> 6;
    int c = c0 + cl;
    float sum = 0.f, sq = 0.f;
    if (c < CIN_) {
        for (int s = sl; s < SEQ_; s += 4) {
            float v = x[((size_t)b*SEQ_ + s)*CIN_ + c];
            sum += v; sq += v*v;
        }
    }
    __shared__ float ssum[4][64], ssq[4][64];
    ssum[sl][cl] = sum; ssq[sl][cl] = sq;
    __syncthreads();
    if (sl == 0 && c < CIN_) {
        float s = ssum[0][cl]+ssum[1][cl]+ssum[2][cl]+ssum[3][cl];
        float q = ssq[0][cl]+ssq[1][cl]+ssq[2][cl]+ssq[3][cl];
        float mn = s * (1.f/SEQ_);
        float var = q * (1.f/SEQ_) - mn*mn;
        meanb[b*CIN_ + c] = mn;
        stdb[b*CIN_ + c]  = sqrtf(var + 1e-5f);
    }
}

// ============================ normalize + transpose (writes bf16) ============================
__global__ __launch_bounds__(256) void norm_transpose(const float* __restrict__ x,
                                                      const float* __restrict__ meanb,
                                                      const float* __restrict__ stdb,
                                                      const float* __restrict__ rw,
                                                      const float* __restrict__ rb,
                                                      ushort_t* __restrict__ xt)
{
    __shared__ float tile[64][65];
    int b = blockIdx.x, s0 = blockIdx.y*64, c0 = blockIdx.z*64;
    int cl = threadIdx.x & 63, sl = threadIdx.x >> 6;
    #pragma unroll
    for (int i = 0; i < 16; ++i) {
        int s = s0 + sl + i*4;
        int c = c0 + cl;
        float v = 0.f;
        if (c < CIN_) v = x[((size_t)b*SEQ_ + s)*CIN_ + c];
        tile[sl + i*4][cl] = v;
    }
    __syncthreads();
    int sl2 = threadIdx.x & 63, cl2 = threadIdx.x >> 6;
    #pragma unroll
    for (int i = 0; i < 16; ++i) {
        int c = c0 + cl2 + i*4;
        if (c >= CIN_) continue;
        int m = b*CIN_ + c;
        float v = tile[sl2][cl2 + i*4];
        v = (v - meanb[m]) / stdb[m] * rw[c] + rb[c];
        xt[(size_t)m*SEQ_ + s0 + sl2] = f2bf(v);
    }
}

// ============================ depthwise causal conv + SiLU (dual write) ============================
__global__ __launch_bounds__(256) void conv_silu(const float* __restrict__ xz,
                                                 const float* __restrict__ cw,
                                                 const float* __restrict__ cb,
                                                 float* __restrict__ xc,
                                                 ushort_t* __restrict__ xcb, int im)
{
    int m = blockIdx.x;  // b*L_+l
    int d = blockIdx.y*256 + threadIdx.x;
    int b = m / L_, l = m - b*L_;
    float4 w = ((const float4*)cw)[(size_t)im*DI_ + d];
    float wv[4] = {w.x, w.y, w.z, w.w};
    float a = cb[im*DI_ + d];
    #pragma unroll
    for (int j = 0; j < 4; ++j) {
        int ls = l - 3 + j;
        if (ls >= 0) a += xz[((size_t)(b*L_ + ls))*(2*DI_) + d] * wv[j];
    }
    float o = a * sigmoidf_(a);
    xc[(size_t)m*DI_ + d] = o;
    xcb[(size_t)m*DI_ + d] = f2bf(o);
}

// ============================ selective scan v4 ============================
// 256 blocks x 64 threads (1 wave/block, barrier-free). (64,1) launch bounds so the
// double-buffered prefetch lives in VGPRs (R3's 64-VGPR cap spilled it to scratch).
// Fast path: A_log = log(arange(1..16)) broadcast => dA[n] = e1^(n+1), 1 exp/step.
__global__ __launch_bounds__(64, 1) void scan_v4(const float* __restrict__ dl,
                                                 const float* __restrict__ xc,
                                                 float* __restrict__ xz,
                                                 const float* __restrict__ dbl,
                                                 const float* __restrict__ A_log,
                                                 const float* __restrict__ Dp, int im)
{
    const int b = blockIdx.x >> 4;
    const int lane = threadIdx.x;
    const int d = ((blockIdx.x & 15) << 6) + lane;
    float a[NST_];
    #pragma unroll
    for (int n = 0; n < NST_; ++n)
        a[n] = -__expf(A_log[((size_t)im*DI_ + d)*NST_ + n]);
    bool uni = true;
    #pragma unroll
    for (int n = 1; n < NST_; ++n)
        uni = uni && (fabsf(a[n] - (n+1)*a[0]) <= 1e-3f*(n+1));
    const float a0 = a[0];
    const float Dd = Dp[im*DI_ + d];
    float h[NST_] = {};
    __shared__ float sBC[2][256];
    float dv[2][8], xv[2][8], zv[2][8], bc[2][4];
    ushort_t* yb = (ushort_t*)xz;

    auto prefetch = [&](int tbase, int nb) {
        #pragma unroll
        for (int i = 0; i < 8; ++i) {
            int t = tbase + i; int tc = (t < L_) ? t : (L_-1);
            size_t rtok = (size_t)(b*L_ + tc);
            dv[nb][i] = dl[rtok*DI_ + d];
            xv[nb][i] = xc[rtok*DI_ + d];
            zv[nb][i] = xz[rtok*2*DI_ + DI_ + d];
        }
        #pragma unroll
        for (int i = 0; i < 4; ++i) {
            int idx = lane + (i << 6);
            int t = tbase + (idx >> 5);
            int tc = (t < L_) ? t : (L_-1);
            bc[nb][i] = dbl[((size_t)(b*L_ + tc))*64 + 32 + (idx & 31)];
        }
    };
    auto step = [&](int t, float dvv, float xvv, float zvv, const float* bcp) {
        float du = dvv * xvv;
        float y = 0.f;
        if (uni) {
            float e1 = __expf(dvv * a0);
            float dAn = e1;
            #pragma unroll
            for (int n = 0; n < NST_; ++n) {
                h[n] = dAn*h[n] + du*bcp[n];
                y += h[n]*bcp[16+n];
                dAn *= e1;
            }
        } else {
            #pragma unroll
            for (int n = 0; n < NST_; ++n) {
                float dA = __expf(dvv * a[n]);
                h[n] = dA*h[n] + du*bcp[n];
                y += h[n]*bcp[16+n];
            }
        }
        y = (y + Dd*xvv) * (zvv * sigmoidf_(zvv));
        yb[((size_t)(b*L_ + t))*4096 + d] = f2bf(y);
    };

    prefetch(0, 0);
    #pragma unroll
    for (int i = 0; i < 4; ++i) sBC[0][lane + (i<<6)] = bc[0][i];

    int buf = 0;
    for (int t0 = 0; t0 < L_-1; t0 += 8, buf ^= 1) {
        const int nb = buf ^ 1;
        prefetch(t0 + 8, nb);
        #pragma unroll
        for (int i = 0; i < 8; ++i)
            step(t0 + i, dv[buf][i], xv[buf][i], zv[buf][i], &sBC[buf][i*32]);
        #pragma unroll
        for (int i = 0; i < 4; ++i) sBC[nb][lane + (i<<6)] = bc[nb][i];
    }
    // tail: t = 320 (L_-1), sits in slot 0 of current buf
    step(L_-1, dv[buf][0], xv[buf][0], zv[buf][0], &sBC[buf][0]);
}

// ============================ launch ============================
extern "C" void kernel_launch(void* const* d_in, const int* in_sizes, int n_in,
                              void* d_out, int out_size, void* d_ws, size_t ws_size,
                              hipStream_t stream)
{
    const float* x      = (const float*)d_in[0];
    const float* rw     = (const float*)d_in[1];
    const float* rb     = (const float*)d_in[2];
    const float* lin1_w = (const float*)d_in[3];
    const float* lin1_b = (const float*)d_in[4];
    const float* head_w = (const float*)d_in[5];
    const float* head_b = (const float*)d_in[6];
    const float* ipw    = (const float*)d_in[7];
    const float* cw     = (const float*)d_in[8];
    const float* cb     = (const float*)d_in[9];
    const float* xpw    = (const float*)d_in[10];
    const float* dpw    = (const float*)d_in[11];
    const float* dpb    = (const float*)d_in[12];
    const float* A_log  = (const float*)d_in[13];
    const float* Dp     = (const float*)d_in[14];
    const float* opw    = (const float*)d_in[15];
    float* out = (float*)d_out;

    float* ws = (float*)d_ws;
    size_t off = 0;
    auto alloc = [&](size_t nfloats) { float* p = ws + off; off += (nfloats + 63) & ~(size_t)63; return p; };
    float* meanb = alloc(NT_);
    float* stdb  = alloc(NT_);
    ushort_t* xnt_bf = (ushort_t*)alloc((size_t)PADM_*DM_/2);
    ushort_t* tbf    = (ushort_t*)alloc((size_t)PADM_*DM_/2);
    float* tb0   = alloc((size_t)NT_*DM_);
    float* tb1   = alloc((size_t)NT_*DM_);
    float* xz    = alloc((size_t)PADM_*2*DI_);   // fp32 xz; first half re-used as bf16 y (stride 4096 ushorts)
    float* xc    = alloc((size_t)NT_*DI_);
    ushort_t* xcb = (ushort_t*)alloc((size_t)PADM_*DI_/2);
    float* dl    = alloc((size_t)NT_*DI_);
    float* dblb  = alloc((size_t)NT_*64);
    ushort_t* lin1_bf = (ushort_t*)alloc((size_t)DM_*SEQ_/2);
    ushort_t* head_bf = (ushort_t*)alloc((size_t)128*DM_/2);      // 96 -> 128 rows padded
    ushort_t* ipw_bf  = (ushort_t*)alloc((size_t)2*2*DI_*DM_/2);
    ushort_t* opw_bf  = (ushort_t*)alloc((size_t)2*DM_*DI_/2);
    ushort_t* xpw_bf  = (ushort_t*)alloc((size_t)2*128*DI_/2);    // 64 -> 128 rows padded per im
    (void)ws_size; (void)in_sizes; (void)n_in; (void)out_size;

    dim3 blk(256);
    const int MT64  = (NT_ + 63) / 64;     // 81
    const int MT128 = (NT_ + 127) / 128;   // 41
    auto cvt = [&](const float* s, ushort_t* d, int n) {
        int n4 = n / 4;
        f32_to_bf16v<<<dim3((n4+255)/256), blk, 0, stream>>>((const float4*)s, (ushort4*)d, n4);
    };

    // weight conversion (per launch; ~8 us total)
    cvt(lin1_w, lin1_bf, DM_*SEQ_);
    cvt(head_w, head_bf, PRED_*DM_);
    cvt(ipw,    ipw_bf,  2*2*DI_*DM_);
    cvt(opw,    opw_bf,  2*DM_*DI_);
    cvt(xpw,             xpw_bf,            64*DI_);
    cvt(xpw + 64*DI_,    xpw_bf + 128*DI_,  64*DI_);

    revin_stats<<<dim3(B_, 6), blk, 0, stream>>>(x, meanb, stdb);
    norm_transpose<<<dim3(B_, 8, 6), blk, 0, stream>>>(x, meanb, stdb, rw, rb, xnt_bf);
    gemm_bf16<<<dim3(MT128, DM_/128), blk, 0, stream>>>(xnt_bf, SEQ_, lin1_bf, SEQ_,
                                                        NT_, DM_, SEQ_,
                                                        EpiBiasDual{tb0, tbf, DM_, lin1_b});

    float* tin = tb0; float* tout = tb1;
    for (int layer = 0; layer < 2; ++layer) {
        hipMemcpyAsync(tout, tin, (size_t)NT_*DM_*sizeof(float), hipMemcpyDeviceToDevice, stream);
        for (int dir = 0; dir < 2; ++dir) {
            const int im = dir;
            // in_proj: xz = t @ ipw[im]^T  (dir=1: rows stored flipped => bwd token order)
            gemm_bf16<<<dim3(MT128, (2*DI_)/128), blk, 0, stream>>>(
                tbf, DM_, ipw_bf + (size_t)im*2*DI_*DM_, DM_,
                NT_, 2*DI_, DM_, EpiStoreF{xz, 2*DI_, dir});
            conv_silu<<<dim3(NT_, DI_/256), blk, 0, stream>>>(xz, cw, cb, xc, xcb, im);
            // x_proj: dbl = xc @ xpw[im]^T   [bf16 MFMA, N=64 in a 128-tile]
            gemm_bf16<<<dim3(MT128, 1), blk, 0, stream>>>(
                xcb, DI_, xpw_bf + (size_t)im*128*DI_, DI_,
                NT_, 64, DI_, EpiStore32{dblb, 64});
            // delta = softplus(dt @ dpw^T + dpb)   [fp32, exp-sensitive]
            gemm_tn<<<dim3(MT64, DI_/64), blk, 0, stream>>>(dblb, 64, dpw + (size_t)im*DI_*RNK_, RNK_,
                                                            NT_, DI_, RNK_,
                                                            EpiSoftplusBias{dl, DI_, dpb + im*DI_});
            scan_v4<<<dim3(256), dim3(64), 0, stream>>>(dl, xc, xz, dblb, A_log, Dp, im);
            // out_proj: tout += y @ opw[im]^T (dir=1: flip back + produce bf16 residual copy)
            if (dir == 0)
                gemm_bf16<<<dim3(MT128, DM_/128), blk, 0, stream>>>(
                    (const ushort_t*)xz, 4*DI_, opw_bf, DI_,
                    NT_, DM_, DI_, EpiAcc{tout, DM_});
            else
                gemm_bf16<<<dim3(MT128, DM_/128), blk, 0, stream>>>(
                    (const ushort_t*)xz, 4*DI_, opw_bf + (size_t)DM_*DI_, DI_,
                    NT_, DM_, DI_, EpiAccFlipDual{tout, tbf, DM_});
        }
        float* tmp = tin; tin = tout; tout = tmp;
    }
    gemm_bf16<<<dim3(MT128, 1), blk, 0, stream>>>(tbf, DM_, head_bf, DM_, NT_, PRED_, DM_,
                                                  EpiHead{out, head_b, meanb, stdb, rw, rb});
}

// Round 5
// 1296.384 us; speedup vs baseline: 3.0536x; 1.2552x over previous
//
#include <hip/hip_runtime.h>
#include <hip/hip_bf16.h>
#include <cstdint>
#include <cstddef>

#define B_    16
#define SEQ_  512
#define CIN_  321
#define PRED_ 96
#define DM_   512
#define DI_   1024
#define NST_  16
#define RNK_  32
#define L_    321
#define NT_   (B_*CIN_)   // 5136 tokens
#define PADM_ 5248        // NT_ padded to multiple of 128 for OOB-safe tile reads

typedef unsigned short ushort_t;
typedef __bf16 bf16x8 __attribute__((ext_vector_type(8)));
typedef float  f32x4  __attribute__((ext_vector_type(4)));
typedef __attribute__((address_space(3))) void lds_void_t;
typedef const __attribute__((address_space(1))) void gbl_void_t;

__device__ __forceinline__ float sigmoidf_(float x){ return 1.f/(1.f+__expf(-x)); }
__device__ __forceinline__ float softplusf_(float x){ return (x>20.f) ? x : log1pf(__expf(x)); }
__device__ __forceinline__ ushort_t f2bf(float f){
    union { float f; unsigned u; } v; v.f = f;
    unsigned r = v.u + 0x7FFF + ((v.u >> 16) & 1);
    return (ushort_t)(r >> 16);
}

// ============================ epilogues ============================
struct EpiStoreF {            // fp32 store, optional token flip (bwd branch)
    float* C; int ldc; int flip;
    __device__ void operator()(int m, int n, float v) const {
        int mm = m;
        if (flip) { int b = m / L_; int l = m - b*L_; mm = b*L_ + (L_-1 - l); }
        C[(size_t)mm*ldc + n] = v;
    }
};
struct EpiBiasDual {          // fp32 + bf16 copy (embed -> residual + GEMM input)
    float* C; ushort_t* Cb; int ldc; const float* bias;
    __device__ void operator()(int m, int n, float v) const {
        float o = v + bias[n];
        C[(size_t)m*ldc + n] = o;
        Cb[(size_t)m*ldc + n] = f2bf(o);
    }
};
struct EpiSoftplusBias {
    float* C; int ldc; const float* bias;
    __device__ void operator()(int m, int n, float v) const {
        C[(size_t)m*ldc + n] = softplusf_(v + bias[n]);
    }
};
struct EpiAcc {               // fwd out_proj: accumulate into residual
    float* C; int ldc;
    __device__ void operator()(int m, int n, float v) const {
        C[(size_t)m*ldc + n] += v;
    }
};
struct EpiAccFlipDual {       // bwd out_proj: accumulate flipped + bf16 copy of final residual
    float* C; ushort_t* Cb; int ldc;
    __device__ void operator()(int m, int n, float v) const {
        int b = m / L_; int l = m - b*L_; int mm = b*L_ + (L_-1 - l);
        float o = C[(size_t)mm*ldc + n] + v;
        C[(size_t)mm*ldc + n] = o;
        Cb[(size_t)mm*ldc + n] = f2bf(o);
    }
};
struct EpiStore32 {
    float* C; int ldc;
    __device__ void operator()(int m, int n, float v) const { C[(size_t)m*ldc + n] = v; }
};
struct EpiHead {
    float* out; const float* bias; const float* mean; const float* stdv;
    const float* rw; const float* rb;
    __device__ void operator()(int m, int n, float v) const {
        int b = m / CIN_, c = m - b*CIN_;
        float o = v + bias[n];
        o = (o - rb[c]) / (rw[c] + 1e-10f);
        o = o * stdv[m] + mean[m];
        out[((size_t)b*PRED_ + n)*CIN_ + c] = o;
    }
};

// ============================ bf16 MFMA GEMM (TN), m97-style staging ============================
template<typename Epi>
__global__ __launch_bounds__(256) void gemm_bf16(const ushort_t* __restrict__ A, int lda,
                                                 const ushort_t* __restrict__ Bw, int ldb,
                                                 int M, int N, int K, Epi epi)
{
    __shared__ __align__(16) ushort_t As[128*32];
    __shared__ __align__(16) ushort_t Bs[128*32];
    const int tid  = threadIdx.x;
    const int m0 = blockIdx.x * 128, n0 = blockIdx.y * 128;
    const int wave = tid >> 6, lane = tid & 63;
    const int wm = (wave & 1) * 64, wn = (wave >> 1) * 64;
    const int ln16 = lane & 15, quad = lane >> 4;
    const int srow = lane >> 2, scol = (lane & 3) * 8;

    const ushort_t* Ag = A + (size_t)(m0 + wave*32 + srow)*lda + scol;
    const ushort_t* Bg = Bw + (size_t)(n0 + wave*32 + srow)*ldb + scol;
    ushort_t* AsW = As + wave*32*32;
    ushort_t* BsW = Bs + wave*32*32;

    f32x4 acc[4][4] = {};
    for (int k0 = 0; k0 < K; k0 += 32) {
        __builtin_amdgcn_global_load_lds((gbl_void_t*)(Ag + k0),                  (lds_void_t*)AsW,           16, 0, 0);
        __builtin_amdgcn_global_load_lds((gbl_void_t*)(Ag + k0 + 16*(size_t)lda), (lds_void_t*)(AsW + 16*32), 16, 0, 0);
        __builtin_amdgcn_global_load_lds((gbl_void_t*)(Bg + k0),                  (lds_void_t*)BsW,           16, 0, 0);
        __builtin_amdgcn_global_load_lds((gbl_void_t*)(Bg + k0 + 16*(size_t)ldb), (lds_void_t*)(BsW + 16*32), 16, 0, 0);
        __syncthreads();
        bf16x8 af[4], bfr[4];
        #pragma unroll
        for (int i = 0; i < 4; ++i)
            af[i] = *(const bf16x8*)(As + (wm + i*16 + ln16)*32 + quad*8);
        #pragma unroll
        for (int i = 0; i < 4; ++i)
            bfr[i] = *(const bf16x8*)(Bs + (wn + i*16 + ln16)*32 + quad*8);
        #pragma unroll
        for (int mi = 0; mi < 4; ++mi)
            #pragma unroll
            for (int ni = 0; ni < 4; ++ni)
                acc[mi][ni] = __builtin_amdgcn_mfma_f32_16x16x32_bf16(af[mi], bfr[ni], acc[mi][ni], 0, 0, 0);
        __syncthreads();
    }
    #pragma unroll
    for (int mi = 0; mi < 4; ++mi) {
        #pragma unroll
        for (int r = 0; r < 4; ++r) {
            int m = m0 + wm + mi*16 + quad*4 + r;
            if (m >= M) continue;
            #pragma unroll
            for (int ni = 0; ni < 4; ++ni) {
                int n = n0 + wn + ni*16 + ln16;
                if (n < N) epi(m, n, acc[mi][ni][r]);
            }
        }
    }
}

// ============================ fp32 GEMM (TN) — precision-sensitive dt matmul ============================
template<typename Epi>
__global__ __launch_bounds__(256) void gemm_tn(const float* __restrict__ A, int lda,
                                               const float* __restrict__ Bw, int ldb,
                                               int M, int N, int K, Epi epi)
{
    constexpr int BM = 64, BN = 64, BK = 32;
    __shared__ __align__(16) float As[BK][BM+4];
    __shared__ __align__(16) float Bs[BK][BN+4];
    const int tid = threadIdx.x;
    const int m0 = blockIdx.x * BM;
    const int n0 = blockIdx.y * BN;
    const int tx = tid & 15, ty = tid >> 4;
    const int ka = tid & (BK-1);
    const int ra = tid >> 5;

    float acc[4][4] = {};
    for (int k0 = 0; k0 < K; k0 += BK) {
        #pragma unroll
        for (int i = 0; i < 8; ++i) {
            int m = ra + i*8;
            int gm = m0 + m;
            float v = 0.f;
            if (gm < M) v = A[(size_t)gm*lda + k0 + ka];
            As[ka][m] = v;
        }
        #pragma unroll
        for (int i = 0; i < 8; ++i) {
            int n = ra + i*8;
            int gn = n0 + n;
            float v = 0.f;
            if (gn < N) v = Bw[(size_t)gn*ldb + k0 + ka];
            Bs[ka][n] = v;
        }
        __syncthreads();
        #pragma unroll
        for (int kk = 0; kk < BK; ++kk) {
            float a4[4], b4[4];
            #pragma unroll
            for (int i = 0; i < 4; ++i) a4[i] = As[kk][ty*4 + i];
            #pragma unroll
            for (int j = 0; j < 4; ++j) b4[j] = Bs[kk][tx*4 + j];
            #pragma unroll
            for (int i = 0; i < 4; ++i)
                #pragma unroll
                for (int j = 0; j < 4; ++j)
                    acc[i][j] += a4[i] * b4[j];
        }
        __syncthreads();
    }
    #pragma unroll
    for (int i = 0; i < 4; ++i) {
        int m = m0 + ty*4 + i;
        if (m >= M) continue;
        #pragma unroll
        for (int j = 0; j < 4; ++j) {
            int n = n0 + tx*4 + j;
            if (n >= N) continue;
            epi(m, n, acc[i][j]);
        }
    }
}

// ============================ fp32 -> bf16 convert ============================
__global__ __launch_bounds__(256) void f32_to_bf16v(const float4* __restrict__ s,
                                                    ushort4* __restrict__ d, int n4)
{
    int i = blockIdx.x*256 + threadIdx.x;
    if (i < n4) {
        float4 v = s[i];
        ushort4 u; u.x=f2bf(v.x); u.y=f2bf(v.y); u.z=f2bf(v.z); u.w=f2bf(v.w);
        d[i] = u;
    }
}

// ============================ RevIN stats ============================
__global__ __launch_bounds__(256) void revin_stats(const float* __restrict__ x,
                                                   float* __restrict__ meanb,
                                                   float* __restrict__ stdb)
{
    int b = blockIdx.x;
    int c0 = blockIdx.y * 64;
    int cl = threadIdx.x & 63;
    int sl = threadIdx.x >> 6;
    int c = c0 + cl;
    float sum = 0.f, sq = 0.f;
    if (c < CIN_) {
        for (int s = sl; s < SEQ_; s += 4) {
            float v = x[((size_t)b*SEQ_ + s)*CIN_ + c];
            sum += v; sq += v*v;
        }
    }
    __shared__ float ssum[4][64], ssq[4][64];
    ssum[sl][cl] = sum; ssq[sl][cl] = sq;
    __syncthreads();
    if (sl == 0 && c < CIN_) {
        float s = ssum[0][cl]+ssum[1][cl]+ssum[2][cl]+ssum[3][cl];
        float q = ssq[0][cl]+ssq[1][cl]+ssq[2][cl]+ssq[3][cl];
        float mn = s * (1.f/SEQ_);
        float var = q * (1.f/SEQ_) - mn*mn;
        meanb[b*CIN_ + c] = mn;
        stdb[b*CIN_ + c]  = sqrtf(var + 1e-5f);
    }
}

// ============================ normalize + transpose (writes bf16) ============================
__global__ __launch_bounds__(256) void norm_transpose(const float* __restrict__ x,
                                                      const float* __restrict__ meanb,
                                                      const float* __restrict__ stdb,
                                                      const float* __restrict__ rw,
                                                      const float* __restrict__ rb,
                                                      ushort_t* __restrict__ xt)
{
    __shared__ float tile[64][65];
    int b = blockIdx.x, s0 = blockIdx.y*64, c0 = blockIdx.z*64;
    int cl = threadIdx.x & 63, sl = threadIdx.x >> 6;
    #pragma unroll
    for (int i = 0; i < 16; ++i) {
        int s = s0 + sl + i*4;
        int c = c0 + cl;
        float v = 0.f;
        if (c < CIN_) v = x[((size_t)b*SEQ_ + s)*CIN_ + c];
        tile[sl + i*4][cl] = v;
    }
    __syncthreads();
    int sl2 = threadIdx.x & 63, cl2 = threadIdx.x >> 6;
    #pragma unroll
    for (int i = 0; i < 16; ++i) {
        int c = c0 + cl2 + i*4;
        if (c >= CIN_) continue;
        int m = b*CIN_ + c;
        float v = tile[sl2][cl2 + i*4];
        v = (v - meanb[m]) / stdb[m] * rw[c] + rb[c];
        xt[(size_t)m*SEQ_ + s0 + sl2] = f2bf(v);
    }
}

// ============================ depthwise causal conv + SiLU (dual write) ============================
__global__ __launch_bounds__(256) void conv_silu(const float* __restrict__ xz,
                                                 const float* __restrict__ cw,
                                                 const float* __restrict__ cb,
                                                 float* __restrict__ xc,
                                                 ushort_t* __restrict__ xcb, int im)
{
    int m = blockIdx.x;  // b*L_+l
    int d = blockIdx.y*256 + threadIdx.x;
    int b = m / L_, l = m - b*L_;
    float4 w = ((const float4*)cw)[(size_t)im*DI_ + d];
    float wv[4] = {w.x, w.y, w.z, w.w};
    float a = cb[im*DI_ + d];
    #pragma unroll
    for (int j = 0; j < 4; ++j) {
        int ls = l - 3 + j;
        if (ls >= 0) a += xz[((size_t)(b*L_ + ls))*(2*DI_) + d] * wv[j];
    }
    float o = a * sigmoidf_(a);
    xc[(size_t)m*DI_ + d] = o;
    xcb[(size_t)m*DI_ + d] = f2bf(o);
}

// ============================ selective scan v5 ============================
// 256 blocks x 64 threads (1 wave/block, barrier-free). Double buffer via TWO
// statically-named register sets, loop unrolled 2 chunks (16 steps) per iter so
// every array index is compile-time => full VGPR promotion (R4's runtime-indexed
// buffers were demoted to scratch: VGPR_Count=76, one memory stall per step).
// sched_barrier(0) pins each prefetch block ahead of the following compute.
__global__ __launch_bounds__(64, 1) void scan_v5(const float* __restrict__ dl,
                                                 const float* __restrict__ xc,
                                                 float* __restrict__ xz,
                                                 const float* __restrict__ dbl,
                                                 const float* __restrict__ A_log,
                                                 const float* __restrict__ Dp, int im)
{
    const int b = blockIdx.x >> 4;
    const int lane = threadIdx.x;
    const int d = ((blockIdx.x & 15) << 6) + lane;
    float a[NST_];
    #pragma unroll
    for (int n = 0; n < NST_; ++n)
        a[n] = -__expf(A_log[((size_t)im*DI_ + d)*NST_ + n]);
    bool uni = true;
    #pragma unroll
    for (int n = 1; n < NST_; ++n)
        uni = uni && (fabsf(a[n] - (n+1)*a[0]) <= 1e-3f*(n+1));
    const float a0 = a[0];
    const float Dd = Dp[im*DI_ + d];
    float h[NST_] = {};
    __shared__ float sBC[2][256];
    ushort_t* yb = (ushort_t*)xz;

    float dvA[8], xvA[8], zvA[8], bcA[4];
    float dvB[8], xvB[8], zvB[8], bcB[4];

    auto pref = [&](int tbase, float (&dv_)[8], float (&xv_)[8], float (&zv_)[8], float (&bc_)[4]) {
        #pragma unroll
        for (int i = 0; i < 8; ++i) {
            int t = tbase + i; int tc = (t < L_) ? t : (L_-1);
            size_t rtok = (size_t)(b*L_ + tc);
            dv_[i] = dl[rtok*DI_ + d];
            xv_[i] = xc[rtok*DI_ + d];
            zv_[i] = xz[rtok*2*DI_ + DI_ + d];
        }
        #pragma unroll
        for (int i = 0; i < 4; ++i) {
            int idx = lane + (i << 6);
            int t = tbase + (idx >> 5);
            int tc = (t < L_) ? t : (L_-1);
            bc_[i] = dbl[((size_t)(b*L_ + tc))*64 + 32 + (idx & 31)];
        }
    };
    auto step = [&](int t, float dvv, float xvv, float zvv, const float* bcp) {
        float du = dvv * xvv;
        float y = 0.f;
        if (uni) {
            float e1 = __expf(dvv * a0);
            float dAn = e1;
            #pragma unroll
            for (int n = 0; n < NST_; ++n) {
                h[n] = dAn*h[n] + du*bcp[n];
                y += h[n]*bcp[16+n];
                dAn *= e1;
            }
        } else {
            #pragma unroll
            for (int n = 0; n < NST_; ++n) {
                float dA = __expf(dvv * a[n]);
                h[n] = dA*h[n] + du*bcp[n];
                y += h[n]*bcp[16+n];
            }
        }
        y = (y + Dd*xvv) * (zvv * sigmoidf_(zvv));
        yb[((size_t)(b*L_ + t))*4096 + d] = f2bf(y);
    };

    pref(0, dvA, xvA, zvA, bcA);
    // L_ = 321 = 20*16 + 1: steady loop covers t = 0..319, one tail step.
    #pragma unroll 1
    for (int t0 = 0; t0 < 320; t0 += 16) {
        pref(t0 + 8, dvB, xvB, zvB, bcB);
        __builtin_amdgcn_sched_barrier(0);
        #pragma unroll
        for (int i = 0; i < 4; ++i) sBC[0][lane + (i<<6)] = bcA[i];
        #pragma unroll
        for (int i = 0; i < 8; ++i)
            step(t0 + i, dvA[i], xvA[i], zvA[i], &sBC[0][i*32]);
        pref(t0 + 16, dvA, xvA, zvA, bcA);
        __builtin_amdgcn_sched_barrier(0);
        #pragma unroll
        for (int i = 0; i < 4; ++i) sBC[1][lane + (i<<6)] = bcB[i];
        #pragma unroll
        for (int i = 0; i < 8; ++i)
            step(t0 + 8 + i, dvB[i], xvB[i], zvB[i], &sBC[1][i*32]);
    }
    // tail: t = 320, prefetched into set A by the last iteration
    #pragma unroll
    for (int i = 0; i < 4; ++i) sBC[0][lane + (i<<6)] = bcA[i];
    step(320, dvA[0], xvA[0], zvA[0], &sBC[0][0]);
}

// ============================ launch ============================
extern "C" void kernel_launch(void* const* d_in, const int* in_sizes, int n_in,
                              void* d_out, int out_size, void* d_ws, size_t ws_size,
                              hipStream_t stream)
{
    const float* x      = (const float*)d_in[0];
    const float* rw     = (const float*)d_in[1];
    const float* rb     = (const float*)d_in[2];
    const float* lin1_w = (const float*)d_in[3];
    const float* lin1_b = (const float*)d_in[4];
    const float* head_w = (const float*)d_in[5];
    const float* head_b = (const float*)d_in[6];
    const float* ipw    = (const float*)d_in[7];
    const float* cw     = (const float*)d_in[8];
    const float* cb     = (const float*)d_in[9];
    const float* xpw    = (const float*)d_in[10];
    const float* dpw    = (const float*)d_in[11];
    const float* dpb    = (const float*)d_in[12];
    const float* A_log  = (const float*)d_in[13];
    const float* Dp     = (const float*)d_in[14];
    const float* opw    = (const float*)d_in[15];
    float* out = (float*)d_out;

    float* ws = (float*)d_ws;
    size_t off = 0;
    auto alloc = [&](size_t nfloats) { float* p = ws + off; off += (nfloats + 63) & ~(size_t)63; return p; };
    float* meanb = alloc(NT_);
    float* stdb  = alloc(NT_);
    ushort_t* xnt_bf = (ushort_t*)alloc((size_t)PADM_*DM_/2);
    ushort_t* tbf    = (ushort_t*)alloc((size_t)PADM_*DM_/2);
    float* tb0   = alloc((size_t)NT_*DM_);
    float* tb1   = alloc((size_t)NT_*DM_);
    float* xz    = alloc((size_t)PADM_*2*DI_);   // fp32 xz; first half re-used as bf16 y (stride 4096 ushorts)
    float* xc    = alloc((size_t)NT_*DI_);
    ushort_t* xcb = (ushort_t*)alloc((size_t)PADM_*DI_/2);
    float* dl    = alloc((size_t)NT_*DI_);
    float* dblb  = alloc((size_t)NT_*64);
    ushort_t* lin1_bf = (ushort_t*)alloc((size_t)DM_*SEQ_/2);
    ushort_t* head_bf = (ushort_t*)alloc((size_t)128*DM_/2);      // 96 -> 128 rows padded
    ushort_t* ipw_bf  = (ushort_t*)alloc((size_t)2*2*DI_*DM_/2);
    ushort_t* opw_bf  = (ushort_t*)alloc((size_t)2*DM_*DI_/2);
    ushort_t* xpw_bf  = (ushort_t*)alloc((size_t)2*128*DI_/2);    // 64 -> 128 rows padded per im
    (void)ws_size; (void)in_sizes; (void)n_in; (void)out_size;

    dim3 blk(256);
    const int MT64  = (NT_ + 63) / 64;     // 81
    const int MT128 = (NT_ + 127) / 128;   // 41
    auto cvt = [&](const float* s, ushort_t* d, int n) {
        int n4 = n / 4;
        f32_to_bf16v<<<dim3((n4+255)/256), blk, 0, stream>>>((const float4*)s, (ushort4*)d, n4);
    };

    // weight conversion (per launch; ~8 us total)
    cvt(lin1_w, lin1_bf, DM_*SEQ_);
    cvt(head_w, head_bf, PRED_*DM_);
    cvt(ipw,    ipw_bf,  2*2*DI_*DM_);
    cvt(opw,    opw_bf,  2*DM_*DI_);
    cvt(xpw,             xpw_bf,            64*DI_);
    cvt(xpw + 64*DI_,    xpw_bf + 128*DI_,  64*DI_);

    revin_stats<<<dim3(B_, 6), blk, 0, stream>>>(x, meanb, stdb);
    norm_transpose<<<dim3(B_, 8, 6), blk, 0, stream>>>(x, meanb, stdb, rw, rb, xnt_bf);
    gemm_bf16<<<dim3(MT128, DM_/128), blk, 0, stream>>>(xnt_bf, SEQ_, lin1_bf, SEQ_,
                                                        NT_, DM_, SEQ_,
                                                        EpiBiasDual{tb0, tbf, DM_, lin1_b});

    float* tin = tb0; float* tout = tb1;
    for (int layer = 0; layer < 2; ++layer) {
        hipMemcpyAsync(tout, tin, (size_t)NT_*DM_*sizeof(float), hipMemcpyDeviceToDevice, stream);
        for (int dir = 0; dir < 2; ++dir) {
            const int im = dir;
            // in_proj: xz = t @ ipw[im]^T  (dir=1: rows stored flipped => bwd token order)
            gemm_bf16<<<dim3(MT128, (2*DI_)/128), blk, 0, stream>>>(
                tbf, DM_, ipw_bf + (size_t)im*2*DI_*DM_, DM_,
                NT_, 2*DI_, DM_, EpiStoreF{xz, 2*DI_, dir});
            conv_silu<<<dim3(NT_, DI_/256), blk, 0, stream>>>(xz, cw, cb, xc, xcb, im);
            // x_proj: dbl = xc @ xpw[im]^T   [bf16 MFMA, N=64 in a 128-tile]
            gemm_bf16<<<dim3(MT128, 1), blk, 0, stream>>>(
                xcb, DI_, xpw_bf + (size_t)im*128*DI_, DI_,
                NT_, 64, DI_, EpiStore32{dblb, 64});
            // delta = softplus(dt @ dpw^T + dpb)   [fp32, exp-sensitive]
            gemm_tn<<<dim3(MT64, DI_/64), blk, 0, stream>>>(dblb, 64, dpw + (size_t)im*DI_*RNK_, RNK_,
                                                            NT_, DI_, RNK_,
                                                            EpiSoftplusBias{dl, DI_, dpb + im*DI_});
            scan_v5<<<dim3(256), dim3(64), 0, stream>>>(dl, xc, xz, dblb, A_log, Dp, im);
            // out_proj: tout += y @ opw[im]^T (dir=1: flip back + produce bf16 residual copy)
            if (dir == 0)
                gemm_bf16<<<dim3(MT128, DM_/128), blk, 0, stream>>>(
                    (const ushort_t*)xz, 4*DI_, opw_bf, DI_,
                    NT_, DM_, DI_, EpiAcc{tout, DM_});
            else
                gemm_bf16<<<dim3(MT128, DM_/128), blk, 0, stream>>>(
                    (const ushort_t*)xz, 4*DI_, opw_bf + (size_t)DM_*DI_, DI_,
                    NT_, DM_, DI_, EpiAccFlipDual{tout, tbf, DM_});
        }
        float* tmp = tin; tin = tout; tout = tmp;
    }
    gemm_bf16<<<dim3(MT128, 1), blk, 0, stream>>>(tbf, DM_, head_bf, DM_, NT_, PRED_, DM_,
                                                  EpiHead{out, head_b, meanb, stdb, rw, rb});
}

// Round 6
// 753.326 us; speedup vs baseline: 5.2548x; 1.7209x over previous
//
#include <hip/hip_runtime.h>
#include <hip/hip_bf16.h>
#include <cstdint>
#include <cstddef>

#define B_    16
#define SEQ_  512
#define CIN_  321
#define PRED_ 96
#define DM_   512
#define DI_   1024
#define NST_  16
#define RNK_  32
#define L_    321
#define NT_   (B_*CIN_)   // 5136 tokens
#define PADM_ 5248        // NT_ padded to multiple of 128 for OOB-safe tile reads
#define TC_   41          // scan chunk length (8 chunks: 7x41 + 34)
#define NC_   8

typedef unsigned short ushort_t;
typedef __bf16 bf16x8 __attribute__((ext_vector_type(8)));
typedef float  f32x4  __attribute__((ext_vector_type(4)));
typedef __attribute__((address_space(3))) void lds_void_t;
typedef const __attribute__((address_space(1))) void gbl_void_t;

__device__ __forceinline__ float sigmoidf_(float x){ return 1.f/(1.f+__expf(-x)); }
__device__ __forceinline__ float softplusf_(float x){ return (x>20.f) ? x : log1pf(__expf(x)); }
__device__ __forceinline__ ushort_t f2bf(float f){
    union { float f; unsigned u; } v; v.f = f;
    unsigned r = v.u + 0x7FFF + ((v.u >> 16) & 1);
    return (ushort_t)(r >> 16);
}
__device__ __forceinline__ float bf2f(ushort_t u){
    return __uint_as_float(((unsigned)u) << 16);
}

// ============================ epilogues (z-batched: epi(z,m,n,v)) ============================
struct EpiBiasDual {          // embed: fp32 residual + bf16 copy
    float* C; ushort_t* Cb; const float* bias;
    __device__ void operator()(int z, int m, int n, float v) const {
        float o = v + bias[n];
        C[(size_t)m*DM_ + n] = o;
        Cb[(size_t)m*DM_ + n] = f2bf(o);
    }
};
struct EpiXZ {                // in_proj: bf16 store, rows flipped for z=1 (bwd token order)
    ushort_t* xzb;
    __device__ void operator()(int z, int m, int n, float v) const {
        int mm = m;
        if (z) { int b = m / L_; int l = m - b*L_; mm = b*L_ + (L_-1 - l); }
        xzb[(size_t)z*PADM_*2*DI_ + (size_t)mm*(2*DI_) + n] = f2bf(v);
    }
};
struct EpiDbl {               // x_proj: fp32, only n<64 valid
    float* C;
    __device__ void operator()(int z, int m, int n, float v) const {
        if (n < 64) C[(size_t)z*NT_*64 + (size_t)m*64 + n] = v;
    }
};
struct EpiSpB {               // dt_proj: softplus(v + bias)
    float* C; const float* bias;
    __device__ void operator()(int z, int m, int n, float v) const {
        C[(size_t)z*NT_*DI_ + (size_t)m*DI_ + n] = softplusf_(v + bias[z*DI_ + n]);
    }
};
struct EpiP {                 // out_proj: fp32 partial into P[z] (reuses dl buffer)
    float* P;
    __device__ void operator()(int z, int m, int n, float v) const {
        P[(size_t)z*NT_*DI_ + (size_t)m*DM_ + n] = v;
    }
};
struct EpiHead {
    float* out; const float* bias; const float* mean; const float* stdv;
    const float* rw; const float* rb;
    __device__ void operator()(int z, int m, int n, float v) const {
        int b = m / CIN_, c = m - b*CIN_;
        float o = v + bias[n];
        o = (o - rb[c]) / (rw[c] + 1e-10f);
        o = o * stdv[m] + mean[m];
        out[((size_t)b*PRED_ + n)*CIN_ + c] = o;
    }
};

// ============================ bf16 MFMA GEMM (TN), z-batched ============================
template<typename Epi>
__global__ __launch_bounds__(256) void gemm_bf16(const ushort_t* __restrict__ A, int lda, size_t zsa,
                                                 const ushort_t* __restrict__ Bw, int ldb, size_t zsb,
                                                 int M, int N, int K, Epi epi)
{
    __shared__ __align__(16) ushort_t As[128*32];
    __shared__ __align__(16) ushort_t Bs[128*32];
    const int z = blockIdx.z;
    A += (size_t)z*zsa; Bw += (size_t)z*zsb;
    const int tid  = threadIdx.x;
    const int m0 = blockIdx.x * 128, n0 = blockIdx.y * 128;
    const int wave = tid >> 6, lane = tid & 63;
    const int wm = (wave & 1) * 64, wn = (wave >> 1) * 64;
    const int ln16 = lane & 15, quad = lane >> 4;
    const int srow = lane >> 2, scol = (lane & 3) * 8;

    const ushort_t* Ag = A + (size_t)(m0 + wave*32 + srow)*lda + scol;
    const ushort_t* Bg = Bw + (size_t)(n0 + wave*32 + srow)*ldb + scol;
    ushort_t* AsW = As + wave*32*32;
    ushort_t* BsW = Bs + wave*32*32;

    f32x4 acc[4][4] = {};
    for (int k0 = 0; k0 < K; k0 += 32) {
        __builtin_amdgcn_global_load_lds((gbl_void_t*)(Ag + k0),                  (lds_void_t*)AsW,           16, 0, 0);
        __builtin_amdgcn_global_load_lds((gbl_void_t*)(Ag + k0 + 16*(size_t)lda), (lds_void_t*)(AsW + 16*32), 16, 0, 0);
        __builtin_amdgcn_global_load_lds((gbl_void_t*)(Bg + k0),                  (lds_void_t*)BsW,           16, 0, 0);
        __builtin_amdgcn_global_load_lds((gbl_void_t*)(Bg + k0 + 16*(size_t)ldb), (lds_void_t*)(BsW + 16*32), 16, 0, 0);
        __syncthreads();
        bf16x8 af[4], bfr[4];
        #pragma unroll
        for (int i = 0; i < 4; ++i)
            af[i] = *(const bf16x8*)(As + (wm + i*16 + ln16)*32 + quad*8);
        #pragma unroll
        for (int i = 0; i < 4; ++i)
            bfr[i] = *(const bf16x8*)(Bs + (wn + i*16 + ln16)*32 + quad*8);
        #pragma unroll
        for (int mi = 0; mi < 4; ++mi)
            #pragma unroll
            for (int ni = 0; ni < 4; ++ni)
                acc[mi][ni] = __builtin_amdgcn_mfma_f32_16x16x32_bf16(af[mi], bfr[ni], acc[mi][ni], 0, 0, 0);
        __syncthreads();
    }
    #pragma unroll
    for (int mi = 0; mi < 4; ++mi) {
        #pragma unroll
        for (int r = 0; r < 4; ++r) {
            int m = m0 + wm + mi*16 + quad*4 + r;
            if (m >= M) continue;
            #pragma unroll
            for (int ni = 0; ni < 4; ++ni) {
                int n = n0 + wn + ni*16 + ln16;
                if (n < N) epi(z, m, n, acc[mi][ni][r]);
            }
        }
    }
}

// ============================ fp32 GEMM (TN), z-batched — dt matmul ============================
template<typename Epi>
__global__ __launch_bounds__(256) void gemm_tn(const float* __restrict__ A, int lda, size_t zsa,
                                               const float* __restrict__ Bw, int ldb, size_t zsb,
                                               int M, int N, int K, Epi epi)
{
    constexpr int BM = 64, BN = 64, BK = 32;
    __shared__ __align__(16) float As[BK][BM+4];
    __shared__ __align__(16) float Bs[BK][BN+4];
    const int z = blockIdx.z;
    A += (size_t)z*zsa; Bw += (size_t)z*zsb;
    const int tid = threadIdx.x;
    const int m0 = blockIdx.x * BM;
    const int n0 = blockIdx.y * BN;
    const int tx = tid & 15, ty = tid >> 4;
    const int ka = tid & (BK-1);
    const int ra = tid >> 5;

    float acc[4][4] = {};
    for (int k0 = 0; k0 < K; k0 += BK) {
        #pragma unroll
        for (int i = 0; i < 8; ++i) {
            int m = ra + i*8;
            int gm = m0 + m;
            float v = 0.f;
            if (gm < M) v = A[(size_t)gm*lda + k0 + ka];
            As[ka][m] = v;
        }
        #pragma unroll
        for (int i = 0; i < 8; ++i) {
            int n = ra + i*8;
            int gn = n0 + n;
            float v = 0.f;
            if (gn < N) v = Bw[(size_t)gn*ldb + k0 + ka];
            Bs[ka][n] = v;
        }
        __syncthreads();
        #pragma unroll
        for (int kk = 0; kk < BK; ++kk) {
            float a4[4], b4[4];
            #pragma unroll
            for (int i = 0; i < 4; ++i) a4[i] = As[kk][ty*4 + i];
            #pragma unroll
            for (int j = 0; j < 4; ++j) b4[j] = Bs[kk][tx*4 + j];
            #pragma unroll
            for (int i = 0; i < 4; ++i)
                #pragma unroll
                for (int j = 0; j < 4; ++j)
                    acc[i][j] += a4[i] * b4[j];
        }
        __syncthreads();
    }
    #pragma unroll
    for (int i = 0; i < 4; ++i) {
        int m = m0 + ty*4 + i;
        if (m >= M) continue;
        #pragma unroll
        for (int j = 0; j < 4; ++j) {
            int n = n0 + tx*4 + j;
            if (n >= N) continue;
            epi(z, m, n, acc[i][j]);
        }
    }
}

// ============================ fp32 -> bf16 convert ============================
__global__ __launch_bounds__(256) void f32_to_bf16v(const float4* __restrict__ s,
                                                    ushort4* __restrict__ d, int n4)
{
    int i = blockIdx.x*256 + threadIdx.x;
    if (i < n4) {
        float4 v = s[i];
        ushort4 u; u.x=f2bf(v.x); u.y=f2bf(v.y); u.z=f2bf(v.z); u.w=f2bf(v.w);
        d[i] = u;
    }
}

// ============================ RevIN stats ============================
__global__ __launch_bounds__(256) void revin_stats(const float* __restrict__ x,
                                                   float* __restrict__ meanb,
                                                   float* __restrict__ stdb)
{
    int b = blockIdx.x;
    int c0 = blockIdx.y * 64;
    int cl = threadIdx.x & 63;
    int sl = threadIdx.x >> 6;
    int c = c0 + cl;
    float sum = 0.f, sq = 0.f;
    if (c < CIN_) {
        for (int s = sl; s < SEQ_; s += 4) {
            float v = x[((size_t)b*SEQ_ + s)*CIN_ + c];
            sum += v; sq += v*v;
        }
    }
    __shared__ float ssum[4][64], ssq[4][64];
    ssum[sl][cl] = sum; ssq[sl][cl] = sq;
    __syncthreads();
    if (sl == 0 && c < CIN_) {
        float s = ssum[0][cl]+ssum[1][cl]+ssum[2][cl]+ssum[3][cl];
        float q = ssq[0][cl]+ssq[1][cl]+ssq[2][cl]+ssq[3][cl];
        float mn = s * (1.f/SEQ_);
        float var = q * (1.f/SEQ_) - mn*mn;
        meanb[b*CIN_ + c] = mn;
        stdb[b*CIN_ + c]  = sqrtf(var + 1e-5f);
    }
}

// ============================ normalize + transpose (writes bf16) ============================
__global__ __launch_bounds__(256) void norm_transpose(const float* __restrict__ x,
                                                      const float* __restrict__ meanb,
                                                      const float* __restrict__ stdb,
                                                      const float* __restrict__ rw,
                                                      const float* __restrict__ rb,
                                                      ushort_t* __restrict__ xt)
{
    __shared__ float tile[64][65];
    int b = blockIdx.x, s0 = blockIdx.y*64, c0 = blockIdx.z*64;
    int cl = threadIdx.x & 63, sl = threadIdx.x >> 6;
    #pragma unroll
    for (int i = 0; i < 16; ++i) {
        int s = s0 + sl + i*4;
        int c = c0 + cl;
        float v = 0.f;
        if (c < CIN_) v = x[((size_t)b*SEQ_ + s)*CIN_ + c];
        tile[sl + i*4][cl] = v;
    }
    __syncthreads();
    int sl2 = threadIdx.x & 63, cl2 = threadIdx.x >> 6;
    #pragma unroll
    for (int i = 0; i < 16; ++i) {
        int c = c0 + cl2 + i*4;
        if (c >= CIN_) continue;
        int m = b*CIN_ + c;
        float v = tile[sl2][cl2 + i*4];
        v = (v - meanb[m]) / stdb[m] * rw[c] + rb[c];
        xt[(size_t)m*SEQ_ + s0 + sl2] = f2bf(v);
    }
}

// ============================ depthwise causal conv + SiLU (bf16 in/out, z-batched) ============================
__global__ __launch_bounds__(256) void conv_silu(const ushort_t* __restrict__ xzb,
                                                 const float* __restrict__ cw,
                                                 const float* __restrict__ cb,
                                                 ushort_t* __restrict__ xcb)
{
    int m = blockIdx.x;  // b*L_+l (possibly flipped order for z=1; consistent downstream)
    int d = blockIdx.y*256 + threadIdx.x;
    int im = blockIdx.z;
    const ushort_t* xz = xzb + (size_t)im*PADM_*2*DI_;
    int b = m / L_, l = m - b*L_;
    float4 w = ((const float4*)cw)[(size_t)im*DI_ + d];
    float wv[4] = {w.x, w.y, w.z, w.w};
    float a = cb[im*DI_ + d];
    #pragma unroll
    for (int j = 0; j < 4; ++j) {
        int ls = l - 3 + j;
        if (ls >= 0) a += bf2f(xz[((size_t)(b*L_ + ls))*(2*DI_) + d]) * wv[j];
    }
    float o = a * sigmoidf_(a);
    xcb[(size_t)im*PADM_*DI_ + (size_t)m*DI_ + d] = f2bf(o);
}

// ============================ chunked selective scan ============================
// Recurrence per (im,b,d,n): h <- exp(delta*a_n)*h + delta*x*B_n ; y = sum_n h*C_n.
// Chunk dA-product = exp(a_n * sum_chunk(delta)). 3 phases, both dirs batched:
//  p1: per (im,b,chunk,d): chunk-local h (h0=0) + S=sum(delta)  -> hloc, Ssum
//  compose: per (im,b,d): 8-step serial carry; hloc overwritten in-place with carry_in
//  p2: per (im,b,chunk,d): rerun chunk from carry_in, emit gated y (bf16 into xzb x-half)
#define SCAN_LOADS(tok)                                                          \
    float dv = dlz[(size_t)(tok)*DI_ + d];                                       \
    float xv = bf2f(xcz[(size_t)(tok)*DI_ + d]);                                 \
    float4 B0 = *(const float4*)(dbz + (size_t)(tok)*64 + 32);                   \
    float4 B1 = *(const float4*)(dbz + (size_t)(tok)*64 + 36);                   \
    float4 B2 = *(const float4*)(dbz + (size_t)(tok)*64 + 40);                   \
    float4 B3 = *(const float4*)(dbz + (size_t)(tok)*64 + 44);                   \
    float Bv[16] = {B0.x,B0.y,B0.z,B0.w, B1.x,B1.y,B1.z,B1.w,                    \
                    B2.x,B2.y,B2.z,B2.w, B3.x,B3.y,B3.z,B3.w};

__global__ __launch_bounds__(64, 3) void scan_p1(const float* __restrict__ dl,
                                                 const ushort_t* __restrict__ xcb,
                                                 const float* __restrict__ dbl,
                                                 const float* __restrict__ A_log,
                                                 float* __restrict__ hloc,
                                                 float* __restrict__ Ssum)
{
    const int im = blockIdx.z >> 4, b = blockIdx.z & 15;
    const int c = blockIdx.y;
    const int d = blockIdx.x*64 + threadIdx.x;
    const float* dlz = dl + (size_t)im*NT_*DI_;
    const ushort_t* xcz = xcb + (size_t)im*PADM_*DI_;
    const float* dbz = dbl + (size_t)im*NT_*64;
    float a[NST_];
    #pragma unroll
    for (int n = 0; n < NST_; ++n)
        a[n] = -__expf(A_log[((size_t)im*DI_ + d)*NST_ + n]);
    bool uni = true;
    #pragma unroll
    for (int n = 1; n < NST_; ++n)
        uni = uni && (fabsf(a[n] - (n+1)*a[0]) <= 1e-3f*(n+1));
    const float a0 = a[0];
    const int t0 = c*TC_, tend = (t0 + TC_ < L_) ? t0 + TC_ : L_;
    float h[NST_] = {};
    float S = 0.f;
    if (uni) {
        for (int t = t0; t < tend; ++t) {
            int tok = b*L_ + t;
            SCAN_LOADS(tok)
            S += dv;
            float du = dv * xv;
            float e1 = __expf(dv * a0), dAn = e1;
            #pragma unroll
            for (int n = 0; n < NST_; ++n) { h[n] = dAn*h[n] + du*Bv[n]; dAn *= e1; }
        }
    } else {
        for (int t = t0; t < tend; ++t) {
            int tok = b*L_ + t;
            SCAN_LOADS(tok)
            S += dv;
            float du = dv * xv;
            #pragma unroll
            for (int n = 0; n < NST_; ++n) h[n] = __expf(dv*a[n])*h[n] + du*Bv[n];
        }
    }
    size_t base = ((size_t)(im*16 + b)*NC_ + c);
    Ssum[base*DI_ + d] = S;
    #pragma unroll
    for (int n = 0; n < NST_; ++n)
        hloc[(base*NST_ + n)*DI_ + d] = h[n];
}

__global__ __launch_bounds__(64, 3) void scan_compose(const float* __restrict__ A_log,
                                                      float* __restrict__ hloc,
                                                      const float* __restrict__ Ssum)
{
    const int im = blockIdx.z >> 4, b = blockIdx.z & 15;
    const int d = blockIdx.x*64 + threadIdx.x;
    float a[NST_];
    #pragma unroll
    for (int n = 0; n < NST_; ++n)
        a[n] = -__expf(A_log[((size_t)im*DI_ + d)*NST_ + n]);
    float carry[NST_] = {};
    for (int c = 0; c < NC_; ++c) {
        size_t base = ((size_t)(im*16 + b)*NC_ + c);
        float S = Ssum[base*DI_ + d];
        #pragma unroll
        for (int n = 0; n < NST_; ++n) {
            size_t idx = (base*NST_ + n)*DI_ + d;
            float hl = hloc[idx];
            hloc[idx] = carry[n];                       // carry_in for pass 2
            carry[n] = __expf(a[n]*S)*carry[n] + hl;
        }
    }
}

__global__ __launch_bounds__(64, 3) void scan_p2(const float* __restrict__ dl,
                                                 const ushort_t* __restrict__ xcb,
                                                 ushort_t* __restrict__ xzb,
                                                 const float* __restrict__ dbl,
                                                 const float* __restrict__ A_log,
                                                 const float* __restrict__ Dp,
                                                 const float* __restrict__ hloc)
{
    const int im = blockIdx.z >> 4, b = blockIdx.z & 15;
    const int c = blockIdx.y;
    const int d = blockIdx.x*64 + threadIdx.x;
    const float* dlz = dl + (size_t)im*NT_*DI_;
    const ushort_t* xcz = xcb + (size_t)im*PADM_*DI_;
    const float* dbz = dbl + (size_t)im*NT_*64;
    ushort_t* xzz = xzb + (size_t)im*PADM_*2*DI_;
    float a[NST_];
    #pragma unroll
    for (int n = 0; n < NST_; ++n)
        a[n] = -__expf(A_log[((size_t)im*DI_ + d)*NST_ + n]);
    bool uni = true;
    #pragma unroll
    for (int n = 1; n < NST_; ++n)
        uni = uni && (fabsf(a[n] - (n+1)*a[0]) <= 1e-3f*(n+1));
    const float a0 = a[0];
    const float Dd = Dp[im*DI_ + d];
    const int t0 = c*TC_, tend = (t0 + TC_ < L_) ? t0 + TC_ : L_;
    size_t base = ((size_t)(im*16 + b)*NC_ + c);
    float h[NST_];
    #pragma unroll
    for (int n = 0; n < NST_; ++n)
        h[n] = hloc[(base*NST_ + n)*DI_ + d];
    if (uni) {
        for (int t = t0; t < tend; ++t) {
            int tok = b*L_ + t;
            SCAN_LOADS(tok)
            float4 C0 = *(const float4*)(dbz + (size_t)tok*64 + 48);
            float4 C1 = *(const float4*)(dbz + (size_t)tok*64 + 52);
            float4 C2 = *(const float4*)(dbz + (size_t)tok*64 + 56);
            float4 C3 = *(const float4*)(dbz + (size_t)tok*64 + 60);
            float Cv[16] = {C0.x,C0.y,C0.z,C0.w, C1.x,C1.y,C1.z,C1.w,
                            C2.x,C2.y,C2.z,C2.w, C3.x,C3.y,C3.z,C3.w};
            float zg = bf2f(xzz[(size_t)tok*2*DI_ + DI_ + d]);
            float du = dv * xv;
            float y = 0.f;
            float e1 = __expf(dv * a0), dAn = e1;
            #pragma unroll
            for (int n = 0; n < NST_; ++n) {
                h[n] = dAn*h[n] + du*Bv[n];
                y += h[n]*Cv[n];
                dAn *= e1;
            }
            y = (y + Dd*xv) * (zg * sigmoidf_(zg));
            xzz[(size_t)tok*2*DI_ + d] = f2bf(y);
        }
    } else {
        for (int t = t0; t < tend; ++t) {
            int tok = b*L_ + t;
            SCAN_LOADS(tok)
            float4 C0 = *(const float4*)(dbz + (size_t)tok*64 + 48);
            float4 C1 = *(const float4*)(dbz + (size_t)tok*64 + 52);
            float4 C2 = *(const float4*)(dbz + (size_t)tok*64 + 56);
            float4 C3 = *(const float4*)(dbz + (size_t)tok*64 + 60);
            float Cv[16] = {C0.x,C0.y,C0.z,C0.w, C1.x,C1.y,C1.z,C1.w,
                            C2.x,C2.y,C2.z,C2.w, C3.x,C3.y,C3.z,C3.w};
            float zg = bf2f(xzz[(size_t)tok*2*DI_ + DI_ + d]);
            float du = dv * xv;
            float y = 0.f;
            #pragma unroll
            for (int n = 0; n < NST_; ++n) {
                h[n] = __expf(dv*a[n])*h[n] + du*Bv[n];
                y += h[n]*Cv[n];
            }
            y = (y + Dd*xv) * (zg * sigmoidf_(zg));
            xzz[(size_t)tok*2*DI_ + d] = f2bf(y);
        }
    }
}

// ============================ fused residual: t += P0 + flip(P1); tbf = bf16(t) ============================
__global__ __launch_bounds__(256) void fuse_res(float* __restrict__ t,
                                                ushort_t* __restrict__ tbf,
                                                const float* __restrict__ P)
{
    const int row4 = DM_/4;   // 128 float4 per row
    size_t i = (size_t)blockIdx.x*256 + threadIdx.x;
    int m = (int)(i / row4), c4 = (int)(i - (size_t)m*row4);
    int b = m / L_, l = m - b*L_;
    int mf = b*L_ + (L_-1 - l);
    float4 tv = ((float4*)t)[i];
    float4 p0 = ((const float4*)P)[(size_t)m*row4 + c4];
    float4 p1 = ((const float4*)(P + (size_t)NT_*DI_))[(size_t)mf*row4 + c4];
    tv.x += p0.x + p1.x; tv.y += p0.y + p1.y;
    tv.z += p0.z + p1.z; tv.w += p0.w + p1.w;
    ((float4*)t)[i] = tv;
    ushort4 u; u.x=f2bf(tv.x); u.y=f2bf(tv.y); u.z=f2bf(tv.z); u.w=f2bf(tv.w);
    ((ushort4*)tbf)[i] = u;
}

// ============================ launch ============================
extern "C" void kernel_launch(void* const* d_in, const int* in_sizes, int n_in,
                              void* d_out, int out_size, void* d_ws, size_t ws_size,
                              hipStream_t stream)
{
    const float* x      = (const float*)d_in[0];
    const float* rw     = (const float*)d_in[1];
    const float* rb     = (const float*)d_in[2];
    const float* lin1_w = (const float*)d_in[3];
    const float* lin1_b = (const float*)d_in[4];
    const float* head_w = (const float*)d_in[5];
    const float* head_b = (const float*)d_in[6];
    const float* ipw    = (const float*)d_in[7];
    const float* cw     = (const float*)d_in[8];
    const float* cb     = (const float*)d_in[9];
    const float* xpw    = (const float*)d_in[10];
    const float* dpw    = (const float*)d_in[11];
    const float* dpb    = (const float*)d_in[12];
    const float* A_log  = (const float*)d_in[13];
    const float* Dp     = (const float*)d_in[14];
    const float* opw    = (const float*)d_in[15];
    float* out = (float*)d_out;

    float* ws = (float*)d_ws;
    size_t off = 0;
    auto alloc = [&](size_t nfloats) { float* p = ws + off; off += (nfloats + 63) & ~(size_t)63; return p; };
    float* meanb = alloc(NT_);
    float* stdb  = alloc(NT_);
    ushort_t* xnt_bf = (ushort_t*)alloc((size_t)PADM_*SEQ_/2);
    ushort_t* tbf    = (ushort_t*)alloc((size_t)PADM_*DM_/2);
    float* tres  = alloc((size_t)NT_*DM_);
    ushort_t* xzb = (ushort_t*)alloc((size_t)2*PADM_*2*DI_/2);   // bf16 xz per dir; x-half later = y
    ushort_t* xcb = (ushort_t*)alloc((size_t)2*PADM_*DI_/2);     // bf16 conv output per dir
    float* dl    = alloc((size_t)2*NT_*DI_);                      // delta per dir; reused as P0/P1
    float* dblb  = alloc((size_t)2*NT_*64);
    float* hloc  = alloc((size_t)2*16*NC_*NST_*DI_);
    float* Ssum  = alloc((size_t)2*16*NC_*DI_);
    ushort_t* lin1_bf = (ushort_t*)alloc((size_t)DM_*SEQ_/2);
    ushort_t* head_bf = (ushort_t*)alloc((size_t)128*DM_/2);      // 96 -> 128 rows padded
    ushort_t* ipw_bf  = (ushort_t*)alloc((size_t)2*2*DI_*DM_/2);
    ushort_t* opw_bf  = (ushort_t*)alloc((size_t)2*DM_*DI_/2);
    ushort_t* xpw_bf  = (ushort_t*)alloc((size_t)2*128*DI_/2);    // 64 -> 128 rows padded per im
    (void)ws_size; (void)in_sizes; (void)n_in; (void)out_size;

    dim3 blk(256);
    auto cvt = [&](const float* s, ushort_t* d, int n) {
        int n4 = n / 4;
        f32_to_bf16v<<<dim3((n4+255)/256), blk, 0, stream>>>((const float4*)s, (ushort4*)d, n4);
    };

    // weight conversion (per launch; ~8 us total)
    cvt(lin1_w, lin1_bf, DM_*SEQ_);
    cvt(head_w, head_bf, PRED_*DM_);
    cvt(ipw,    ipw_bf,  2*2*DI_*DM_);
    cvt(opw,    opw_bf,  2*DM_*DI_);
    cvt(xpw,             xpw_bf,            64*DI_);
    cvt(xpw + 64*DI_,    xpw_bf + 128*DI_,  64*DI_);

    revin_stats<<<dim3(B_, 6), blk, 0, stream>>>(x, meanb, stdb);
    norm_transpose<<<dim3(B_, 8, 6), blk, 0, stream>>>(x, meanb, stdb, rw, rb, xnt_bf);
    gemm_bf16<<<dim3(41, 4, 1), blk, 0, stream>>>(xnt_bf, SEQ_, 0, lin1_bf, SEQ_, 0,
                                                  NT_, DM_, SEQ_,
                                                  EpiBiasDual{tres, tbf, lin1_b});

    for (int layer = 0; layer < 2; ++layer) {
        // in_proj (both dirs): xzb[z] = t @ ipw[z]^T, z=1 rows stored flipped
        gemm_bf16<<<dim3(41, 16, 2), blk, 0, stream>>>(
            tbf, DM_, 0, ipw_bf, DM_, (size_t)2*DI_*DM_,
            NT_, 2*DI_, DM_, EpiXZ{xzb});
        conv_silu<<<dim3(NT_, 4, 2), blk, 0, stream>>>(xzb, cw, cb, xcb);
        // x_proj (both dirs): dblb[z] = xc @ xpw[z]^T (N=64 in 128-tile)
        gemm_bf16<<<dim3(41, 1, 2), blk, 0, stream>>>(
            xcb, DI_, (size_t)PADM_*DI_, xpw_bf, DI_, (size_t)128*DI_,
            NT_, 64, DI_, EpiDbl{dblb});
        // delta (both dirs, fp32): softplus(dt @ dpw^T + dpb)
        gemm_tn<<<dim3(81, 16, 2), blk, 0, stream>>>(
            dblb, 64, (size_t)NT_*64, dpw, RNK_, (size_t)DI_*RNK_,
            NT_, DI_, RNK_, EpiSpB{dl, dpb});
        // chunked scan (both dirs)
        scan_p1<<<dim3(16, NC_, 32), dim3(64), 0, stream>>>(dl, xcb, dblb, A_log, hloc, Ssum);
        scan_compose<<<dim3(16, 1, 32), dim3(64), 0, stream>>>(A_log, hloc, Ssum);
        scan_p2<<<dim3(16, NC_, 32), dim3(64), 0, stream>>>(dl, xcb, xzb, dblb, A_log, Dp, hloc);
        // out_proj (both dirs): P[z] = y @ opw[z]^T (partials into spent dl buffer)
        gemm_bf16<<<dim3(41, 4, 2), blk, 0, stream>>>(
            xzb, 2*DI_, (size_t)PADM_*2*DI_, opw_bf, DI_, (size_t)DM_*DI_,
            NT_, DM_, DI_, EpiP{dl});
        // residual: t += P0 + flip(P1); tbf = bf16(t)
        fuse_res<<<dim3((NT_*DM_/4)/256), blk, 0, stream>>>(tres, tbf, dl);
    }
    gemm_bf16<<<dim3(41, 1, 1), blk, 0, stream>>>(tbf, DM_, 0, head_bf, DM_, 0,
                                                  NT_, PRED_, DM_,
                                                  EpiHead{out, head_b, meanb, stdb, rw, rb});
}